// Round 2
// baseline (495.135 us; speedup 1.0000x reference)
//
#include <hip/hip_runtime.h>
#include <cstdint>
#include <cstddef>

#define B_    4
#define SQ_   4096
#define SK_   1024
#define HID_  640
#define SATD_ 768
#define NH_   10
#define HD_   64

typedef __bf16 bf16_t;
typedef __bf16 bf16x4 __attribute__((ext_vector_type(4)));
typedef __bf16 bf16x8 __attribute__((ext_vector_type(8)));
typedef float  f32x4  __attribute__((ext_vector_type(4)));
typedef unsigned short u16x8 __attribute__((ext_vector_type(8)));

static __device__ __forceinline__ unsigned short f2u(float f) {
  bf16_t b = (bf16_t)f;
  return __builtin_bit_cast(unsigned short, b);
}
static __device__ __forceinline__ float u2f(unsigned short u) {
  return (float)__builtin_bit_cast(bf16_t, u);
}
static __device__ __forceinline__ f32x4 mfma16(bf16x8 a, bf16x8 b, f32x4 c) {
  return __builtin_amdgcn_mfma_f32_16x16x32_bf16(a, b, c, 0, 0, 0);
}
// async global->LDS, 16B per lane; LDS deposit = uniform base + lane*16
static __device__ __forceinline__ void glds16(const unsigned short* g, unsigned short* l) {
  __builtin_amdgcn_global_load_lds((const __attribute__((address_space(1))) void*)g,
                                   (__attribute__((address_space(3))) void*)l, 16, 0, 0);
}

// ---------------- fused weight transposes (4 segments in one launch) ----------------
__global__ void k_transpose4(const float* __restrict__ Wq, const float* __restrict__ Wk,
                             const float* __restrict__ Wv, const float* __restrict__ Wp2,
                             unsigned short* __restrict__ wqT, unsigned short* __restrict__ kvT,
                             unsigned short* __restrict__ wp2T) {
  int seg = blockIdx.y;
  const float* W; unsigned short* D; int K, N;
  if (seg == 0)      { W = Wq;  D = wqT;  K = 640; N = 640; }
  else if (seg == 1) { W = Wk;  D = kvT;  K = 768; N = 640; }
  else if (seg == 2) { W = Wv;  D = kvT + (size_t)640 * 768; K = 768; N = 640; }
  else               { W = Wp2; D = wp2T; K = 640; N = 640; }
  int i = blockIdx.x * 256 + threadIdx.x;
  if (i >= N * K) return;
  int n = i / K, k = i - n * K;
  D[i] = f2u(W[(size_t)k * N + n]);
}

__global__ void k_concat_bias(const float* __restrict__ bk, const float* __restrict__ bv,
                              float* __restrict__ out) {
  int i = blockIdx.x * 256 + threadIdx.x;
  if (i < HID_) out[i] = bk[i];
  else if (i < 2 * HID_) out[i] = bv[i - HID_];
}

// ---------------- sat LayerNorm -> bf16 ----------------
__global__ __launch_bounds__(256) void k_satln(const float* __restrict__ x,
                                               const float* __restrict__ g,
                                               const float* __restrict__ bta,
                                               unsigned short* __restrict__ out) {
  int r = blockIdx.x;
  const float* xr = x + (size_t)r * SATD_;
  int t = threadIdx.x;
  float v0 = xr[t], v1 = xr[t + 256], v2 = xr[t + 512];
  float s = v0 + v1 + v2;
  float ss = v0 * v0 + v1 * v1 + v2 * v2;
  __shared__ float sb[8];
  for (int o = 32; o; o >>= 1) { s += __shfl_xor(s, o); ss += __shfl_xor(ss, o); }
  if ((t & 63) == 0) { sb[t >> 6] = s; sb[4 + (t >> 6)] = ss; }
  __syncthreads();
  s  = sb[0] + sb[1] + sb[2] + sb[3];
  ss = sb[4] + sb[5] + sb[6] + sb[7];
  float m = s * (1.f / SATD_);
  float rstd = rsqrtf(ss * (1.f / SATD_) - m * m + 1e-5f);
  unsigned short* orow = out + (size_t)r * SATD_;
  orow[t]       = f2u((v0 - m) * rstd * g[t]       + bta[t]);
  orow[t + 256] = f2u((v1 - m) * rstd * g[t + 256] + bta[t + 256]);
  orow[t + 512] = f2u((v2 - m) * rstd * g[t + 512] + bta[t + 512]);
}

// ---------------- pf1 = silu(plucker @ Wp1 + bp1) ----------------
__global__ void k_pf1(const float* __restrict__ plk, const float* __restrict__ W,
                      const float* __restrict__ bias, unsigned short* __restrict__ out) {
  int i = blockIdx.x * 256 + threadIdx.x;
  int r = i / HID_, c = i - r * HID_;
  const float* p = plk + (size_t)r * 6;
  float a = bias[c];
#pragma unroll
  for (int j = 0; j < 6; j++) a += p[j] * W[j * HID_ + c];
  out[i] = f2u(a / (1.f + __expf(-a)));
}

// ---------------- GEMM: C[M,N](bf16) = A[M,K] @ BT[N,K]^T + bias ----------------
// m97 structure: unpadded [128][32] tiles, glds width-16 staging, 2 barriers/iter.
template <bool A_IS_F32>
__global__ __launch_bounds__(256) void k_gemm(const void* __restrict__ Ap,
                                              const unsigned short* __restrict__ BT,
                                              const float* __restrict__ bias,
                                              unsigned short* __restrict__ C,
                                              int M, int N, int K) {
  __shared__ unsigned short As[128 * 32];
  __shared__ unsigned short Bs[128 * 32];
  const int bm = blockIdx.x * 128, bn = blockIdx.y * 128;
  const int t = threadIdx.x, wv = t >> 6, lane = t & 63;
  const int lc = lane & 15, quad = lane >> 4;
  const int wm = (wv >> 1) * 64, wn = (wv & 1) * 64;
  f32x4 acc[4][4];
  f32x4 zero = {0.f, 0.f, 0.f, 0.f};
#pragma unroll
  for (int i = 0; i < 4; i++)
#pragma unroll
    for (int j = 0; j < 4; j++) acc[i][j] = zero;
  const int srow = wv * 32 + (lane >> 2);   // glds: +i*16
  const int schunk = (lane & 2) ? ((lane & 3) * 8) : ((lane & 3) * 8); // keep simple below
  const int sc8 = (lane & 3) * 8;

  for (int k0 = 0; k0 < K; k0 += 32) {
    __syncthreads();
    if constexpr (A_IS_F32) {
      const float* ap0 = (const float*)Ap + (size_t)(bm + (t >> 2)) * K + k0 + (t & 3) * 8;
#pragma unroll
      for (int i = 0; i < 2; i++) {
        const float* ap = ap0 + (size_t)i * 64 * K;
        float4 a0 = *(const float4*)ap;
        float4 a1 = *(const float4*)(ap + 4);
        u16x8 u = { f2u(a0.x), f2u(a0.y), f2u(a0.z), f2u(a0.w),
                    f2u(a1.x), f2u(a1.y), f2u(a1.z), f2u(a1.w) };
        *(u16x8*)&As[((t >> 2) + i * 64) * 32 + (t & 3) * 8] = u;
      }
    } else {
#pragma unroll
      for (int i = 0; i < 2; i++)
        glds16((const unsigned short*)Ap + (size_t)(bm + srow + i * 16) * K + k0 + sc8,
               &As[(wv * 32 + i * 16) * 32]);
    }
#pragma unroll
    for (int i = 0; i < 2; i++)
      glds16(BT + (size_t)(bn + srow + i * 16) * K + k0 + sc8,
             &Bs[(wv * 32 + i * 16) * 32]);
    __syncthreads();
    bf16x8 af[4], bfr[4];
#pragma unroll
    for (int mt = 0; mt < 4; mt++) af[mt]  = *(const bf16x8*)&As[(wm + mt * 16 + lc) * 32 + quad * 8];
#pragma unroll
    for (int nt = 0; nt < 4; nt++) bfr[nt] = *(const bf16x8*)&Bs[(wn + nt * 16 + lc) * 32 + quad * 8];
#pragma unroll
    for (int mt = 0; mt < 4; mt++)
#pragma unroll
      for (int nt = 0; nt < 4; nt++) acc[mt][nt] = mfma16(af[mt], bfr[nt], acc[mt][nt]);
  }
#pragma unroll
  for (int mt = 0; mt < 4; mt++) {
    int row = bm + wm + mt * 16 + quad * 4;
#pragma unroll
    for (int nt = 0; nt < 4; nt++) {
      int col = bn + wn + nt * 16 + lc;
      float bsv = bias[col];
#pragma unroll
      for (int r = 0; r < 4; r++)
        C[(size_t)(row + r) * N + col] = f2u(acc[mt][nt][r] + bsv);
    }
  }
}

// ---------------- RoPE in-place (bf16); Q gets 0.125*log2(e) folded in ----------------
__global__ void k_rope(unsigned short* __restrict__ buf, const float* __restrict__ xy,
                       int rows, int rowstride, float qscale) {
  int i = blockIdx.x * 256 + threadIdx.x;
  int d = i & 31;
  int rh = i >> 5;
  int h = rh % NH_;
  int r = rh / NH_;
  if (r >= rows) return;
  float coord = (d < 16) ? xy[(size_t)r * 2] : xy[(size_t)r * 2 + 1];
  int j = d & 15;
  float inv = __expf(-(float)j * (9.210340371976184f / 16.f));
  float ang = coord * inv;
  float cs = __cosf(ang), sn = __sinf(ang);
  size_t base = (size_t)r * rowstride + h * HD_ + d;
  float t1 = u2f(buf[base]), t2 = u2f(buf[base + 32]);
  buf[base]      = f2u((t1 * cs - t2 * sn) * qscale);
  buf[base + 32] = f2u((t1 * sn + t2 * cs) * qscale);
}

// ---------------- gate = sigmoid(LN(hidden + pf2) @ Wg + bg) ----------------
__global__ __launch_bounds__(256) void k_gate(const float* __restrict__ hid,
                                              const unsigned short* __restrict__ pf2,
                                              const float* __restrict__ g,
                                              const float* __restrict__ be,
                                              const float* __restrict__ Wg,
                                              const float* __restrict__ bg,
                                              const float* __restrict__ vm,
                                              float* __restrict__ gate_buf,
                                              float* __restrict__ lg_buf) {
  int r = blockIdx.x;
  const float* hr = hid + (size_t)r * HID_;
  const unsigned short* pr = pf2 + (size_t)r * HID_;
  int t = threadIdx.x;
  __shared__ float xb[HID_];
  __shared__ float sb[8];
  float s = 0.f, ss = 0.f;
  for (int c = t; c < HID_; c += 256) {
    float x = hr[c] + u2f(pr[c]);
    xb[c] = x; s += x; ss += x * x;
  }
  for (int o = 32; o; o >>= 1) { s += __shfl_xor(s, o); ss += __shfl_xor(ss, o); }
  if ((t & 63) == 0) { sb[t >> 6] = s; sb[4 + (t >> 6)] = ss; }
  __syncthreads();
  s  = sb[0] + sb[1] + sb[2] + sb[3];
  ss = sb[4] + sb[5] + sb[6] + sb[7];
  float m = s * (1.f / HID_);
  float rstd = rsqrtf(ss * (1.f / HID_) - m * m + 1e-5f);
  float dacc = 0.f;
  for (int c = t; c < HID_; c += 256)
    dacc += ((xb[c] - m) * rstd * g[c] + be[c]) * Wg[c];
  for (int o = 32; o; o >>= 1) dacc += __shfl_xor(dacc, o);
  __syncthreads();
  if ((t & 63) == 0) sb[t >> 6] = dacc;
  __syncthreads();
  if (t == 0) {
    float dsum = sb[0] + sb[1] + sb[2] + sb[3] + bg[0];
    float gate = 1.f / (1.f + __expf(-dsum));
    float v = vm[r];
    gate_buf[r] = (v > 0.5f) ? gate : 0.f;
    lg_buf[r]   = (v > 0.5f) ? 0.f : gate;
  }
}

// ---------------- V transpose ----------------
__global__ __launch_bounds__(256) void k_transpose_v(const unsigned short* __restrict__ kv_lin,
                                                     unsigned short* __restrict__ vT) {
  __shared__ unsigned short tile[64 * 65];
  const int b = blockIdx.z, kt0 = blockIdx.x * 64, d0 = blockIdx.y * 64;
  const int t = threadIdx.x;
  const int row = t >> 3, c8 = (t & 7) * 8;
#pragma unroll
  for (int i = 0; i < 2; i++) {
    int kk = row + i * 32;
    u16x8 v = *(const u16x8*)(kv_lin + (size_t)(b * SK_ + kt0 + kk) * (2 * HID_) + HID_ + d0 + c8);
#pragma unroll
    for (int u = 0; u < 8; u++) tile[(c8 + u) * 65 + kk] = v[u];
  }
  __syncthreads();
#pragma unroll
  for (int i = 0; i < 2; i++) {
    int dd = row + i * 32;
    u16x8 o;
#pragma unroll
    for (int u = 0; u < 8; u++) o[u] = tile[dd * 65 + c8 + u];
    *(u16x8*)(vT + ((size_t)b * HID_ + d0 + dd) * SK_ + kt0 + c8) = o;
  }
}

// ---------------- attention: barrier-free K-loop, direct-global K/V frags ----------------
// 128 q per block, 32 q per wave (2 groups of 16). exp2-domain softmax
// (Q pre-scaled by 0.125*log2e in k_rope).
__global__ __launch_bounds__(256) void k_attn(const unsigned short* __restrict__ q_lin,
                                              const unsigned short* __restrict__ kv_lin,
                                              const unsigned short* __restrict__ vT,
                                              const float* __restrict__ gate_buf,
                                              float* __restrict__ out) {
  __shared__ unsigned short Pt[4][32 * 72];   // per wave [q][k], stride 72
  const int qb = blockIdx.x * 128;
  const int bh = blockIdx.y;
  const int b = bh / NH_, h = bh - b * NH_;
  const int t = threadIdx.x, wv = t >> 6, lane = t & 63;
  const int lc = lane & 15, quad = lane >> 4;
  unsigned short* myPt = &Pt[wv][0];

  const unsigned short* qbase = q_lin + (size_t)(b * SQ_ + qb + wv * 32 + lc) * HID_ + h * HD_;
  bf16x8 qf[2][2];
#pragma unroll
  for (int g = 0; g < 2; g++) {
    qf[g][0] = *(const bf16x8*)(qbase + (size_t)g * 16 * HID_ + quad * 8);
    qf[g][1] = *(const bf16x8*)(qbase + (size_t)g * 16 * HID_ + 32 + quad * 8);
  }
  f32x4 zero = {0.f, 0.f, 0.f, 0.f};
  f32x4 O[2][4];
#pragma unroll
  for (int g = 0; g < 2; g++)
#pragma unroll
    for (int dt = 0; dt < 4; dt++) O[g][dt] = zero;
  float m_run[2] = {-__builtin_inff(), -__builtin_inff()};
  float l_run[2] = {0.f, 0.f};

  const unsigned short* Kg = kv_lin + (size_t)b * SK_ * (2 * HID_) + h * HD_;
  const unsigned short* Vg = vT + ((size_t)b * HID_ + h * HD_) * SK_;

  for (int kc = 0; kc < SK_; kc += 64) {
    // S^T = K · Q^T : ST[g][kt] rows key=kt*16+quad*4+r, col q=g*16+lc
    f32x4 ST[2][4];
#pragma unroll
    for (int kt = 0; kt < 4; kt++) {
      const unsigned short* kr = Kg + (size_t)(kc + kt * 16 + lc) * (2 * HID_) + quad * 8;
      bf16x8 ka0 = *(const bf16x8*)kr;
      bf16x8 ka1 = *(const bf16x8*)(kr + 32);
#pragma unroll
      for (int g = 0; g < 2; g++)
        ST[g][kt] = mfma16(ka1, qf[g][1], mfma16(ka0, qf[g][0], zero));
    }
    // online softmax (exp2 domain), per q-group
#pragma unroll
    for (int g = 0; g < 2; g++) {
      float mloc = -__builtin_inff();
#pragma unroll
      for (int kt = 0; kt < 4; kt++)
#pragma unroll
        for (int r = 0; r < 4; r++) mloc = fmaxf(mloc, ST[g][kt][r]);
      mloc = fmaxf(mloc, __shfl_xor(mloc, 16));
      mloc = fmaxf(mloc, __shfl_xor(mloc, 32));
      float mnew = fmaxf(m_run[g], mloc);
      float alpha = __builtin_amdgcn_exp2f(m_run[g] - mnew);
      m_run[g] = mnew;
      float rs = 0.f;
#pragma unroll
      for (int kt = 0; kt < 4; kt++) {
        bf16x4 pk;
#pragma unroll
        for (int r = 0; r < 4; r++) {
          float p = __builtin_amdgcn_exp2f(ST[g][kt][r] - mnew);
          rs += p;
          pk[r] = (bf16_t)p;
        }
        *(bf16x4*)&myPt[(g * 16 + lc) * 72 + kt * 16 + quad * 4] = pk;
      }
      rs += __shfl_xor(rs, 16);
      rs += __shfl_xor(rs, 32);
      l_run[g] = l_run[g] * alpha + rs;
#pragma unroll
      for (int dt = 0; dt < 4; dt++) O[g][dt] = O[g][dt] * alpha;
    }
    // O^T += V^T · P^T  (V frags direct from global/L1, P from per-wave LDS)
#pragma unroll
    for (int ks = 0; ks < 2; ks++) {
      bf16x8 va[4];
#pragma unroll
      for (int dt = 0; dt < 4; dt++)
        va[dt] = *(const bf16x8*)(Vg + (size_t)(dt * 16 + lc) * SK_ + kc + ks * 32 + quad * 8);
#pragma unroll
      for (int g = 0; g < 2; g++) {
        bf16x8 pb = *(const bf16x8*)&myPt[(g * 16 + lc) * 72 + ks * 32 + quad * 8];
#pragma unroll
        for (int dt = 0; dt < 4; dt++)
          O[g][dt] = mfma16(va[dt], pb, O[g][dt]);
      }
    }
  }
#pragma unroll
  for (int g = 0; g < 2; g++) {
    int rg = b * SQ_ + qb + wv * 32 + g * 16 + lc;
    float gv = gate_buf[rg] / l_run[g];
    float* orow = out + (size_t)rg * HID_ + h * HD_;
#pragma unroll
    for (int dt = 0; dt < 4; dt++)
#pragma unroll
      for (int r = 0; r < 4; r++)
        orow[dt * 16 + quad * 4 + r] = O[g][dt][r] * gv;
  }
}

// ---------------- loss reduction ----------------
__global__ __launch_bounds__(256) void k_loss(const float* __restrict__ lg,
                                              const float* __restrict__ vm,
                                              float* __restrict__ out_loss) {
  int t = threadIdx.x;
  float s = 0.f, cnt = 0.f;
  for (int i = t; i < B_ * SQ_; i += 256) {
    s += lg[i];
    cnt += (vm[i] > 0.5f) ? 0.f : 1.f;
  }
  __shared__ float sb[8];
  for (int o = 32; o; o >>= 1) { s += __shfl_xor(s, o); cnt += __shfl_xor(cnt, o); }
  if ((t & 63) == 0) { sb[t >> 6] = s; sb[4 + (t >> 6)] = cnt; }
  __syncthreads();
  if (t == 0) {
    s   = sb[0] + sb[1] + sb[2] + sb[3];
    cnt = sb[4] + sb[5] + sb[6] + sb[7];
    out_loss[0] = s / fmaxf(cnt, 1.f) * 0.05f;
  }
}

extern "C" void kernel_launch(void* const* d_in, const int* in_sizes, int n_in,
                              void* d_out, int out_size, void* d_ws, size_t ws_size,
                              hipStream_t stream) {
  (void)in_sizes; (void)n_in; (void)out_size; (void)ws_size;
  const float* hidden = (const float*)d_in[0];
  const float* sat    = (const float*)d_in[1];
  const float* sat_xy = (const float*)d_in[2];
  const float* bev_xy = (const float*)d_in[3];
  const float* plk    = (const float*)d_in[4];
  const float* vm     = (const float*)d_in[5];
  const float* Wq     = (const float*)d_in[6];
  const float* bq     = (const float*)d_in[7];
  const float* slg    = (const float*)d_in[8];
  const float* slb    = (const float*)d_in[9];
  const float* Wk     = (const float*)d_in[10];
  const float* bk     = (const float*)d_in[11];
  const float* Wv     = (const float*)d_in[12];
  const float* bv     = (const float*)d_in[13];
  const float* Wp1    = (const float*)d_in[14];
  const float* bp1    = (const float*)d_in[15];
  const float* Wp2    = (const float*)d_in[16];
  const float* bp2    = (const float*)d_in[17];
  const float* glg    = (const float*)d_in[18];
  const float* glb    = (const float*)d_in[19];
  const float* Wg     = (const float*)d_in[20];
  const float* bg     = (const float*)d_in[21];
  float* out = (float*)d_out;

  char* ws = (char*)d_ws;
  size_t off = 0;
  auto alloc = [&](size_t bytes) -> char* {
    char* p = ws + off;
    off += (bytes + 255) & ~(size_t)255;
    return p;
  };
  unsigned short* regA = (unsigned short*)alloc((size_t)16384 * 640 * 2);  // pf1 -> q_lin
  char* regB = alloc((size_t)16384 * 640 * 2);                              // pf2 -> kv_lin + sn
  unsigned short* pf1    = regA;
  unsigned short* q_lin  = regA;
  unsigned short* pf2    = (unsigned short*)regB;
  unsigned short* kv_lin = (unsigned short*)regB;
  unsigned short* sn     = (unsigned short*)(regB + (size_t)4096 * 1280 * 2);
  unsigned short* vT     = (unsigned short*)alloc((size_t)B_ * HID_ * SK_ * 2);
  unsigned short* wqT    = (unsigned short*)alloc((size_t)640 * 640 * 2);
  unsigned short* kvT    = (unsigned short*)alloc((size_t)1280 * 768 * 2);
  unsigned short* wp2T   = (unsigned short*)alloc((size_t)640 * 640 * 2);
  float* bias_kv  = (float*)alloc(1280 * 4);
  float* gate_buf = (float*)alloc(16384 * 4);
  float* lg_buf   = (float*)alloc(16384 * 4);

  // 1) weight prep (single fused launch)
  {
    dim3 g((768 * 640 + 255) / 256, 4);
    k_transpose4<<<g, 256, 0, stream>>>(Wq, Wk, Wv, Wp2, wqT, kvT, wp2T);
  }
  k_concat_bias<<<5, 256, 0, stream>>>(bk, bv, bias_kv);

  // 2) gate path
  k_pf1<<<16384 * 640 / 256, 256, 0, stream>>>(plk, Wp1, bp1, pf1);
  {
    dim3 g(128, 5);
    k_gemm<false><<<g, 256, 0, stream>>>(pf1, wp2T, bp2, pf2, 16384, 640, 640);
  }
  k_gate<<<16384, 256, 0, stream>>>(hidden, pf2, glg, glb, Wg, bg, vm, gate_buf, lg_buf);

  // 3) sat path
  k_satln<<<4096, 256, 0, stream>>>(sat, slg, slb, sn);
  {
    dim3 g(32, 10);
    k_gemm<false><<<g, 256, 0, stream>>>(sn, kvT, bias_kv, kv_lin, 4096, 1280, 768);
  }

  // 4) Q GEMM, RoPE (Q folds 0.125*log2e for exp2-domain softmax), V transpose
  {
    dim3 g(128, 5);
    k_gemm<true><<<g, 256, 0, stream>>>(hidden, wqT, bq, q_lin, 16384, 640, 640);
  }
  k_rope<<<16384 * NH_ * 32 / 256, 256, 0, stream>>>(q_lin, bev_xy, 16384, 640, 0.18033688011112042f);
  k_rope<<<4096 * NH_ * 32 / 256, 256, 0, stream>>>(kv_lin, sat_xy, 4096, 1280, 1.0f);
  {
    dim3 g(SK_ / 64, HID_ / 64, B_);
    k_transpose_v<<<g, 256, 0, stream>>>(kv_lin, vT);
  }

  // 5) attention + loss
  {
    dim3 g(SQ_ / 128, B_ * NH_);
    k_attn<<<g, 256, 0, stream>>>(q_lin, kv_lin, vT, gate_buf, out);
  }
  k_loss<<<1, 256, 0, stream>>>(lg_buf, vm, out + (size_t)B_ * SQ_ * HID_);
}

// Round 3
// 389.738 us; speedup vs baseline: 1.2704x; 1.2704x over previous
//
#include <hip/hip_runtime.h>
#include <cstdint>
#include <cstddef>

#define B_    4
#define SQ_   4096
#define SK_   1024
#define HID_  640
#define SATD_ 768
#define NH_   10
#define HD_   64

typedef __bf16 bf16_t;
typedef __bf16 bf16x4 __attribute__((ext_vector_type(4)));
typedef __bf16 bf16x8 __attribute__((ext_vector_type(8)));
typedef float  f32x4  __attribute__((ext_vector_type(4)));
typedef unsigned short u16x8 __attribute__((ext_vector_type(8)));

static __device__ __forceinline__ unsigned short f2u(float f) {
  bf16_t b = (bf16_t)f;
  return __builtin_bit_cast(unsigned short, b);
}
static __device__ __forceinline__ float u2f(unsigned short u) {
  return (float)__builtin_bit_cast(bf16_t, u);
}
static __device__ __forceinline__ f32x4 mfma16(bf16x8 a, bf16x8 b, f32x4 c) {
  return __builtin_amdgcn_mfma_f32_16x16x32_bf16(a, b, c, 0, 0, 0);
}
static __device__ __forceinline__ void glds16(const unsigned short* g, unsigned short* l) {
  __builtin_amdgcn_global_load_lds((const __attribute__((address_space(1))) void*)g,
                                   (__attribute__((address_space(3))) void*)l, 16, 0, 0);
}

// ---------------- fused weight transposes ----------------
__global__ void k_transpose4(const float* __restrict__ Wq, const float* __restrict__ Wk,
                             const float* __restrict__ Wv, const float* __restrict__ Wp2,
                             unsigned short* __restrict__ wqT, unsigned short* __restrict__ kvT,
                             unsigned short* __restrict__ wp2T) {
  int seg = blockIdx.y;
  const float* W; unsigned short* D; int K, N;
  if (seg == 0)      { W = Wq;  D = wqT;  K = 640; N = 640; }
  else if (seg == 1) { W = Wk;  D = kvT;  K = 768; N = 640; }
  else if (seg == 2) { W = Wv;  D = kvT + (size_t)640 * 768; K = 768; N = 640; }
  else               { W = Wp2; D = wp2T; K = 640; N = 640; }
  int i = blockIdx.x * 256 + threadIdx.x;
  if (i >= N * K) return;
  int n = i / K, k = i - n * K;
  D[i] = f2u(W[(size_t)k * N + n]);
}

__global__ void k_concat_bias(const float* __restrict__ bk, const float* __restrict__ bv,
                              float* __restrict__ out) {
  int i = blockIdx.x * 256 + threadIdx.x;
  if (i < HID_) out[i] = bk[i];
  else if (i < 2 * HID_) out[i] = bv[i - HID_];
}

// ---------------- sat LayerNorm -> bf16 ----------------
__global__ __launch_bounds__(256) void k_satln(const float* __restrict__ x,
                                               const float* __restrict__ g,
                                               const float* __restrict__ bta,
                                               unsigned short* __restrict__ out) {
  int r = blockIdx.x;
  const float* xr = x + (size_t)r * SATD_;
  int t = threadIdx.x;
  float v0 = xr[t], v1 = xr[t + 256], v2 = xr[t + 512];
  float s = v0 + v1 + v2;
  float ss = v0 * v0 + v1 * v1 + v2 * v2;
  __shared__ float sb[8];
  for (int o = 32; o; o >>= 1) { s += __shfl_xor(s, o); ss += __shfl_xor(ss, o); }
  if ((t & 63) == 0) { sb[t >> 6] = s; sb[4 + (t >> 6)] = ss; }
  __syncthreads();
  s  = sb[0] + sb[1] + sb[2] + sb[3];
  ss = sb[4] + sb[5] + sb[6] + sb[7];
  float m = s * (1.f / SATD_);
  float rstd = rsqrtf(ss * (1.f / SATD_) - m * m + 1e-5f);
  unsigned short* orow = out + (size_t)r * SATD_;
  orow[t]       = f2u((v0 - m) * rstd * g[t]       + bta[t]);
  orow[t + 256] = f2u((v1 - m) * rstd * g[t + 256] + bta[t + 256]);
  orow[t + 512] = f2u((v2 - m) * rstd * g[t + 512] + bta[t + 512]);
}

// ---------------- pf1 = silu(plucker @ Wp1 + bp1) ----------------
__global__ void k_pf1(const float* __restrict__ plk, const float* __restrict__ W,
                      const float* __restrict__ bias, unsigned short* __restrict__ out) {
  int i = blockIdx.x * 256 + threadIdx.x;
  int r = i / HID_, c = i - r * HID_;
  const float* p = plk + (size_t)r * 6;
  float a = bias[c];
#pragma unroll
  for (int j = 0; j < 6; j++) a += p[j] * W[j * HID_ + c];
  out[i] = f2u(a / (1.f + __expf(-a)));
}

// ---------------- GEMM (bf16 A via glds16) with optional fused RoPE epilogue ----------
// C[M,N](bf16) = rope(A @ BT^T + bias) * qscale  (rope applied to cols < rope_cols)
__global__ __launch_bounds__(256) void k_gemm(const unsigned short* __restrict__ A,
                                              const unsigned short* __restrict__ BT,
                                              const float* __restrict__ bias,
                                              unsigned short* __restrict__ C,
                                              int M, int N, int K,
                                              const float* __restrict__ rope_xy,
                                              int rope_cols, float qscale) {
  __shared__ unsigned short As[128 * 32];
  __shared__ unsigned short Bs[128 * 32];
  const int bm = blockIdx.x * 128, bn = blockIdx.y * 128;
  const int t = threadIdx.x, wv = t >> 6, lane = t & 63;
  const int lc = lane & 15, quad = lane >> 4;
  const int wm = (wv >> 1) * 64, wn = (wv & 1) * 64;
  f32x4 acc[4][4];
  f32x4 zero = {0.f, 0.f, 0.f, 0.f};
#pragma unroll
  for (int i = 0; i < 4; i++)
#pragma unroll
    for (int j = 0; j < 4; j++) acc[i][j] = zero;
  const int srow = wv * 32 + (lane >> 2);
  const int sc8 = (lane & 3) * 8;

  for (int k0 = 0; k0 < K; k0 += 32) {
    __syncthreads();
#pragma unroll
    for (int i = 0; i < 2; i++) {
      glds16(A  + (size_t)(bm + srow + i * 16) * K + k0 + sc8, &As[(wv * 32 + i * 16) * 32]);
      glds16(BT + (size_t)(bn + srow + i * 16) * K + k0 + sc8, &Bs[(wv * 32 + i * 16) * 32]);
    }
    __syncthreads();
    bf16x8 af[4], bfr[4];
#pragma unroll
    for (int mt = 0; mt < 4; mt++) af[mt]  = *(const bf16x8*)&As[(wm + mt * 16 + lc) * 32 + quad * 8];
#pragma unroll
    for (int nt = 0; nt < 4; nt++) bfr[nt] = *(const bf16x8*)&Bs[(wn + nt * 16 + lc) * 32 + quad * 8];
#pragma unroll
    for (int mt = 0; mt < 4; mt++)
#pragma unroll
      for (int nt = 0; nt < 4; nt++) acc[mt][nt] = mfma16(af[mt], bfr[nt], acc[mt][nt]);
  }

  float bv[4];
#pragma unroll
  for (int nt = 0; nt < 4; nt++) bv[nt] = bias[bn + wn + nt * 16 + lc];
  const bool dorope = (rope_xy != nullptr) && (bn + wn < rope_cols);
  // inv freq: 10000^(-lc/16) = exp2(-lc * log2(10000)/16)
  const float inv = __builtin_amdgcn_exp2f(-(float)lc * 0.8304820237218407f);

#pragma unroll
  for (int mt = 0; mt < 4; mt++) {
    int row = bm + wm + mt * 16 + quad * 4;
#pragma unroll
    for (int r = 0; r < 4; r++) {
      unsigned short* crow = C + (size_t)(row + r) * N + bn + wn + lc;
      float v0 = acc[mt][0][r] + bv[0];
      float v1 = acc[mt][1][r] + bv[1];
      float v2 = acc[mt][2][r] + bv[2];
      float v3 = acc[mt][3][r] + bv[3];
      if (dorope) {
        float2 xy = *(const float2*)&rope_xy[(size_t)(row + r) * 2];
        float s0, c0, s1, c1;
        __sincosf(xy.x * inv, &s0, &c0);
        __sincosf(xy.y * inv, &s1, &c1);
        float n0 = (v0 * c0 - v2 * s0) * qscale;
        float n2 = (v0 * s0 + v2 * c0) * qscale;
        float n1 = (v1 * c1 - v3 * s1) * qscale;
        float n3 = (v1 * s1 + v3 * c1) * qscale;
        v0 = n0; v1 = n1; v2 = n2; v3 = n3;
      }
      crow[0]  = f2u(v0);
      crow[16] = f2u(v1);
      crow[32] = f2u(v2);
      crow[48] = f2u(v3);
    }
  }
}

// ---------------- gate + hidden->bf16 conversion ----------------
__global__ __launch_bounds__(256) void k_gate(const float* __restrict__ hid,
                                              const unsigned short* __restrict__ pf2,
                                              const float* __restrict__ g,
                                              const float* __restrict__ be,
                                              const float* __restrict__ Wg,
                                              const float* __restrict__ bg,
                                              const float* __restrict__ vm,
                                              float* __restrict__ gate_buf,
                                              float* __restrict__ lg_buf,
                                              unsigned short* __restrict__ hid_bf16) {
  int r = blockIdx.x;
  const float* hr = hid + (size_t)r * HID_;
  const unsigned short* pr = pf2 + (size_t)r * HID_;
  int t = threadIdx.x;
  __shared__ float xb[HID_];
  __shared__ float sb[8];
  float s = 0.f, ss = 0.f;
  for (int c = t; c < HID_; c += 256) {
    float hv = hr[c];
    hid_bf16[(size_t)r * HID_ + c] = f2u(hv);
    float x = hv + u2f(pr[c]);
    xb[c] = x; s += x; ss += x * x;
  }
  for (int o = 32; o; o >>= 1) { s += __shfl_xor(s, o); ss += __shfl_xor(ss, o); }
  if ((t & 63) == 0) { sb[t >> 6] = s; sb[4 + (t >> 6)] = ss; }
  __syncthreads();
  s  = sb[0] + sb[1] + sb[2] + sb[3];
  ss = sb[4] + sb[5] + sb[6] + sb[7];
  float m = s * (1.f / HID_);
  float rstd = rsqrtf(ss * (1.f / HID_) - m * m + 1e-5f);
  float dacc = 0.f;
  for (int c = t; c < HID_; c += 256)
    dacc += ((xb[c] - m) * rstd * g[c] + be[c]) * Wg[c];
  for (int o = 32; o; o >>= 1) dacc += __shfl_xor(dacc, o);
  __syncthreads();
  if ((t & 63) == 0) sb[t >> 6] = dacc;
  __syncthreads();
  if (t == 0) {
    float dsum = sb[0] + sb[1] + sb[2] + sb[3] + bg[0];
    float gate = 1.f / (1.f + __expf(-dsum));
    float v = vm[r];
    gate_buf[r] = (v > 0.5f) ? gate : 0.f;
    lg_buf[r]   = (v > 0.5f) ? 0.f : gate;
  }
}

// ---------------- V transpose ----------------
__global__ __launch_bounds__(256) void k_transpose_v(const unsigned short* __restrict__ kv_lin,
                                                     unsigned short* __restrict__ vT) {
  __shared__ unsigned short tile[64 * 65];
  const int b = blockIdx.z, kt0 = blockIdx.x * 64, d0 = blockIdx.y * 64;
  const int t = threadIdx.x;
  const int row = t >> 3, c8 = (t & 7) * 8;
#pragma unroll
  for (int i = 0; i < 2; i++) {
    int kk = row + i * 32;
    u16x8 v = *(const u16x8*)(kv_lin + (size_t)(b * SK_ + kt0 + kk) * (2 * HID_) + HID_ + d0 + c8);
#pragma unroll
    for (int u = 0; u < 8; u++) tile[(c8 + u) * 65 + kk] = v[u];
  }
  __syncthreads();
#pragma unroll
  for (int i = 0; i < 2; i++) {
    int dd = row + i * 32;
    u16x8 o;
#pragma unroll
    for (int u = 0; u < 8; u++) o[u] = tile[dd * 65 + c8 + u];
    *(u16x8*)(vT + ((size_t)b * HID_ + d0 + dd) * SK_ + kt0 + c8) = o;
  }
}

// ---------------- attention: staged-LDS, 128q/block, 32q/wave, no-max exp2 softmax ----
__global__ __launch_bounds__(256) void k_attn(const unsigned short* __restrict__ q_lin,
                                              const unsigned short* __restrict__ kv_lin,
                                              const unsigned short* __restrict__ vT,
                                              const float* __restrict__ gate_buf,
                                              float* __restrict__ out) {
  __shared__ unsigned short Ks[64 * 72];      // [key][d], stride 72
  __shared__ unsigned short Vt[64 * 72];      // [d][key], stride 72
  __shared__ unsigned short Pt[4][32 * 72];   // per wave [q][key], stride 72
  const int qb = blockIdx.x * 128;
  const int bh = blockIdx.y;
  const int b = bh / NH_, h = bh - b * NH_;
  const int t = threadIdx.x, wv = t >> 6, lane = t & 63;
  const int lc = lane & 15, quad = lane >> 4;
  unsigned short* myPt = &Pt[wv][0];

  // Q frags (B-operand): lane holds Q[q = g*16+lc][d = quad*8+j (+32)]
  const unsigned short* qbase = q_lin + (size_t)(b * SQ_ + qb + wv * 32 + lc) * HID_ + h * HD_;
  bf16x8 qf[2][2];
#pragma unroll
  for (int g = 0; g < 2; g++) {
    qf[g][0] = *(const bf16x8*)(qbase + (size_t)g * 16 * HID_ + quad * 8);
    qf[g][1] = *(const bf16x8*)(qbase + (size_t)g * 16 * HID_ + 32 + quad * 8);
  }
  f32x4 zero = {0.f, 0.f, 0.f, 0.f};
  f32x4 O[2][4];
#pragma unroll
  for (int g = 0; g < 2; g++)
#pragma unroll
    for (int dt = 0; dt < 4; dt++) O[g][dt] = zero;
  float l_run[2] = {0.f, 0.f};

  const unsigned short* Kg = kv_lin + (size_t)b * SK_ * (2 * HID_) + h * HD_;
  const unsigned short* Vg = vT + ((size_t)b * HID_ + h * HD_) * SK_;
  const int srow = t >> 3, scol = (t & 7) * 8;

  for (int kc = 0; kc < SK_; kc += 64) {
    __syncthreads();
#pragma unroll
    for (int i = 0; i < 2; i++) {
      int row = srow + i * 32;
      *(u16x8*)&Ks[row * 72 + scol] = *(const u16x8*)(Kg + (size_t)(kc + row) * (2 * HID_) + scol);
      *(u16x8*)&Vt[row * 72 + scol] = *(const u16x8*)(Vg + (size_t)row * SK_ + kc + scol);
    }
    __syncthreads();

    // S^T = K · Q^T (exp2-domain; Q pre-scaled by 0.125*log2e in GEMM epilogue)
    f32x4 ST[2][4];
#pragma unroll
    for (int kt = 0; kt < 4; kt++) {
      bf16x8 ka0 = *(const bf16x8*)&Ks[(kt * 16 + lc) * 72 + quad * 8];
      bf16x8 ka1 = *(const bf16x8*)&Ks[(kt * 16 + lc) * 72 + 32 + quad * 8];
#pragma unroll
      for (int g = 0; g < 2; g++)
        ST[g][kt] = mfma16(ka1, qf[g][1], mfma16(ka0, qf[g][0], zero));
    }
    // no-max softmax: p = exp2(s); logits bounded (|s·log2e| < ~4), f32-safe
#pragma unroll
    for (int g = 0; g < 2; g++) {
      float rs = 0.f;
#pragma unroll
      for (int kt = 0; kt < 4; kt++) {
        bf16x4 pk;
#pragma unroll
        for (int r = 0; r < 4; r++) {
          float p = __builtin_amdgcn_exp2f(ST[g][kt][r]);
          rs += p;
          pk[r] = (bf16_t)p;
        }
        *(bf16x4*)&myPt[(g * 16 + lc) * 72 + kt * 16 + quad * 4] = pk;
      }
      rs += __shfl_xor(rs, 16);
      rs += __shfl_xor(rs, 32);
      l_run[g] += rs;
    }
    // O^T += V^T · P^T
#pragma unroll
    for (int ks = 0; ks < 2; ks++) {
      bf16x8 va[4];
#pragma unroll
      for (int dt = 0; dt < 4; dt++)
        va[dt] = *(const bf16x8*)&Vt[(dt * 16 + lc) * 72 + ks * 32 + quad * 8];
#pragma unroll
      for (int g = 0; g < 2; g++) {
        bf16x8 pb = *(const bf16x8*)&myPt[(g * 16 + lc) * 72 + ks * 32 + quad * 8];
#pragma unroll
        for (int dt = 0; dt < 4; dt++)
          O[g][dt] = mfma16(va[dt], pb, O[g][dt]);
      }
    }
  }

#pragma unroll
  for (int g = 0; g < 2; g++) {
    int rg = b * SQ_ + qb + wv * 32 + g * 16 + lc;
    float gv = gate_buf[rg] / l_run[g];
    float* orow = out + (size_t)rg * HID_ + h * HD_;
#pragma unroll
    for (int dt = 0; dt < 4; dt++) {
      f32x4 o4 = O[g][dt] * gv;
      *(f32x4*)&orow[dt * 16 + quad * 4] = o4;
    }
  }
}

// ---------------- loss reduction ----------------
__global__ __launch_bounds__(256) void k_loss(const float* __restrict__ lg,
                                              const float* __restrict__ vm,
                                              float* __restrict__ out_loss) {
  int t = threadIdx.x;
  float s = 0.f, cnt = 0.f;
  for (int i = t; i < B_ * SQ_; i += 256) {
    s += lg[i];
    cnt += (vm[i] > 0.5f) ? 0.f : 1.f;
  }
  __shared__ float sb[8];
  for (int o = 32; o; o >>= 1) { s += __shfl_xor(s, o); cnt += __shfl_xor(cnt, o); }
  if ((t & 63) == 0) { sb[t >> 6] = s; sb[4 + (t >> 6)] = cnt; }
  __syncthreads();
  if (t == 0) {
    s   = sb[0] + sb[1] + sb[2] + sb[3];
    cnt = sb[4] + sb[5] + sb[6] + sb[7];
    out_loss[0] = s / fmaxf(cnt, 1.f) * 0.05f;
  }
}

extern "C" void kernel_launch(void* const* d_in, const int* in_sizes, int n_in,
                              void* d_out, int out_size, void* d_ws, size_t ws_size,
                              hipStream_t stream) {
  (void)in_sizes; (void)n_in; (void)out_size; (void)ws_size;
  const float* hidden = (const float*)d_in[0];
  const float* sat    = (const float*)d_in[1];
  const float* sat_xy = (const float*)d_in[2];
  const float* bev_xy = (const float*)d_in[3];
  const float* plk    = (const float*)d_in[4];
  const float* vm     = (const float*)d_in[5];
  const float* Wq     = (const float*)d_in[6];
  const float* bq     = (const float*)d_in[7];
  const float* slg    = (const float*)d_in[8];
  const float* slb    = (const float*)d_in[9];
  const float* Wk     = (const float*)d_in[10];
  const float* bk     = (const float*)d_in[11];
  const float* Wv     = (const float*)d_in[12];
  const float* bv     = (const float*)d_in[13];
  const float* Wp1    = (const float*)d_in[14];
  const float* bp1    = (const float*)d_in[15];
  const float* Wp2    = (const float*)d_in[16];
  const float* bp2    = (const float*)d_in[17];
  const float* glg    = (const float*)d_in[18];
  const float* glb    = (const float*)d_in[19];
  const float* Wg     = (const float*)d_in[20];
  const float* bg     = (const float*)d_in[21];
  float* out = (float*)d_out;

  char* ws = (char*)d_ws;
  size_t off = 0;
  auto alloc = [&](size_t bytes) -> char* {
    char* p = ws + off;
    off += (bytes + 255) & ~(size_t)255;
    return p;
  };
  unsigned short* regA = (unsigned short*)alloc((size_t)16384 * 640 * 2);  // pf1 -> q_lin
  char* regB = alloc((size_t)16384 * 640 * 2);                              // pf2 -> kv_lin + sn
  unsigned short* pf1    = regA;
  unsigned short* q_lin  = regA;
  unsigned short* pf2    = (unsigned short*)regB;
  unsigned short* kv_lin = (unsigned short*)regB;
  unsigned short* sn     = (unsigned short*)(regB + (size_t)4096 * 1280 * 2);
  unsigned short* vT       = (unsigned short*)alloc((size_t)B_ * HID_ * SK_ * 2);
  unsigned short* hid_bf16 = (unsigned short*)alloc((size_t)16384 * 640 * 2);
  unsigned short* wqT    = (unsigned short*)alloc((size_t)640 * 640 * 2);
  unsigned short* kvT    = (unsigned short*)alloc((size_t)1280 * 768 * 2);
  unsigned short* wp2T   = (unsigned short*)alloc((size_t)640 * 640 * 2);
  float* bias_kv  = (float*)alloc(1280 * 4);
  float* gate_buf = (float*)alloc(16384 * 4);
  float* lg_buf   = (float*)alloc(16384 * 4);

  // 1) weight prep
  {
    dim3 g((768 * 640 + 255) / 256, 4);
    k_transpose4<<<g, 256, 0, stream>>>(Wq, Wk, Wv, Wp2, wqT, kvT, wp2T);
  }
  k_concat_bias<<<5, 256, 0, stream>>>(bk, bv, bias_kv);

  // 2) gate path: pf1 -> pf2 GEMM -> gate (also emits hidden in bf16)
  k_pf1<<<16384 * 640 / 256, 256, 0, stream>>>(plk, Wp1, bp1, pf1);
  {
    dim3 g(128, 5);
    k_gemm<<<g, 256, 0, stream>>>(pf1, wp2T, bp2, pf2, 16384, 640, 640, nullptr, 0, 1.f);
  }
  k_gate<<<16384, 256, 0, stream>>>(hidden, pf2, glg, glb, Wg, bg, vm, gate_buf, lg_buf, hid_bf16);

  // 3) sat path: LN -> fused K|V GEMM with RoPE on K half
  k_satln<<<4096, 256, 0, stream>>>(sat, slg, slb, sn);
  {
    dim3 g(32, 10);
    k_gemm<<<g, 256, 0, stream>>>(sn, kvT, bias_kv, kv_lin, 4096, 1280, 768, sat_xy, HID_, 1.f);
  }
  {
    dim3 g(SK_ / 64, HID_ / 64, B_);
    k_transpose_v<<<g, 256, 0, stream>>>(kv_lin, vT);
  }

  // 4) Q GEMM with RoPE + 0.125*log2e scale fused (exp2-domain softmax)
  {
    dim3 g(128, 5);
    k_gemm<<<g, 256, 0, stream>>>(hid_bf16, wqT, bq, q_lin, 16384, 640, 640,
                                  bev_xy, HID_, 0.18033688011112042f);
  }

  // 5) attention + loss
  {
    dim3 g(SQ_ / 128, B_ * NH_);
    k_attn<<<g, 256, 0, stream>>>(q_lin, kv_lin, vT, gate_buf, out);
  }
  k_loss<<<1, 256, 0, stream>>>(lg_buf, vm, out + (size_t)B_ * SQ_ * HID_);
}

// Round 4
// 354.328 us; speedup vs baseline: 1.3974x; 1.0999x over previous
//
#include <hip/hip_runtime.h>
#include <cstdint>
#include <cstddef>

#define B_    4
#define SQ_   4096
#define SK_   1024
#define HID_  640
#define SATD_ 768
#define NH_   10
#define HD_   64

typedef __bf16 bf16_t;
typedef __bf16 bf16x4 __attribute__((ext_vector_type(4)));
typedef __bf16 bf16x8 __attribute__((ext_vector_type(8)));
typedef float  f32x4  __attribute__((ext_vector_type(4)));
typedef unsigned short u16x8 __attribute__((ext_vector_type(8)));

static __device__ __forceinline__ unsigned short f2u(float f) {
  bf16_t b = (bf16_t)f;
  return __builtin_bit_cast(unsigned short, b);
}
static __device__ __forceinline__ float u2f(unsigned short u) {
  return (float)__builtin_bit_cast(bf16_t, u);
}
static __device__ __forceinline__ f32x4 mfma16(bf16x8 a, bf16x8 b, f32x4 c) {
  return __builtin_amdgcn_mfma_f32_16x16x32_bf16(a, b, c, 0, 0, 0);
}
static __device__ __forceinline__ void glds16(const unsigned short* g, unsigned short* l) {
  __builtin_amdgcn_global_load_lds((const __attribute__((address_space(1))) void*)g,
                                   (__attribute__((address_space(3))) void*)l, 16, 0, 0);
}

// ---------------- LDS-tiled weight transpose: W[K][N] f32 -> WT[N][K] bf16 ----------
__global__ __launch_bounds__(256) void k_transpose4(const float* __restrict__ Wq,
                                                    const float* __restrict__ Wk,
                                                    const float* __restrict__ Wv,
                                                    const float* __restrict__ Wp2,
                                                    unsigned short* __restrict__ wqT,
                                                    unsigned short* __restrict__ kvT,
                                                    unsigned short* __restrict__ wp2T) {
  __shared__ unsigned short tile[64 * 65];
  int seg = blockIdx.y;
  const float* W; unsigned short* D; int K;
  if (seg == 0)      { W = Wq;  D = wqT;  K = 640; }
  else if (seg == 1) { W = Wk;  D = kvT;  K = 768; }
  else if (seg == 2) { W = Wv;  D = kvT + (size_t)640 * 768; K = 768; }
  else               { W = Wp2; D = wp2T; K = 640; }
  const int ktiles = K / 64;
  int kt = blockIdx.x % ktiles, ntile = blockIdx.x / ktiles;
  if (ntile >= 10) return;
  const int k0 = kt * 64, n0 = ntile * 64;
  const int t = threadIdx.x, r = t >> 3, c8 = (t & 7) * 8;
#pragma unroll
  for (int i = 0; i < 2; i++) {
    int row = r + i * 32;   // k_local
    const float* wp = W + (size_t)(k0 + row) * HID_ + n0 + c8;
    float4 a0 = *(const float4*)wp, a1 = *(const float4*)(wp + 4);
    tile[(c8 + 0) * 65 + row] = f2u(a0.x);
    tile[(c8 + 1) * 65 + row] = f2u(a0.y);
    tile[(c8 + 2) * 65 + row] = f2u(a0.z);
    tile[(c8 + 3) * 65 + row] = f2u(a0.w);
    tile[(c8 + 4) * 65 + row] = f2u(a1.x);
    tile[(c8 + 5) * 65 + row] = f2u(a1.y);
    tile[(c8 + 6) * 65 + row] = f2u(a1.z);
    tile[(c8 + 7) * 65 + row] = f2u(a1.w);
  }
  __syncthreads();
#pragma unroll
  for (int i = 0; i < 2; i++) {
    int nl = r + i * 32;
    u16x8 o;
#pragma unroll
    for (int u = 0; u < 8; u++) o[u] = tile[nl * 65 + c8 + u];
    *(u16x8*)(D + (size_t)(n0 + nl) * K + k0 + c8) = o;
  }
}

__global__ void k_concat_bias(const float* __restrict__ bk, const float* __restrict__ bv,
                              float* __restrict__ out) {
  int i = blockIdx.x * 256 + threadIdx.x;
  if (i < HID_) out[i] = bk[i];
  else if (i < 2 * HID_) out[i] = bv[i - HID_];
}

// ---------------- sat LayerNorm -> bf16 ----------------
__global__ __launch_bounds__(256) void k_satln(const float* __restrict__ x,
                                               const float* __restrict__ g,
                                               const float* __restrict__ bta,
                                               unsigned short* __restrict__ out) {
  int r = blockIdx.x;
  const float* xr = x + (size_t)r * SATD_;
  int t = threadIdx.x;
  float v0 = xr[t], v1 = xr[t + 256], v2 = xr[t + 512];
  float s = v0 + v1 + v2;
  float ss = v0 * v0 + v1 * v1 + v2 * v2;
  __shared__ float sb[8];
  for (int o = 32; o; o >>= 1) { s += __shfl_xor(s, o); ss += __shfl_xor(ss, o); }
  if ((t & 63) == 0) { sb[t >> 6] = s; sb[4 + (t >> 6)] = ss; }
  __syncthreads();
  s  = sb[0] + sb[1] + sb[2] + sb[3];
  ss = sb[4] + sb[5] + sb[6] + sb[7];
  float m = s * (1.f / SATD_);
  float rstd = rsqrtf(ss * (1.f / SATD_) - m * m + 1e-5f);
  unsigned short* orow = out + (size_t)r * SATD_;
  orow[t]       = f2u((v0 - m) * rstd * g[t]       + bta[t]);
  orow[t + 256] = f2u((v1 - m) * rstd * g[t + 256] + bta[t + 256]);
  orow[t + 512] = f2u((v2 - m) * rstd * g[t + 512] + bta[t + 512]);
}

// ---------------- pf1 = silu(plucker @ Wp1 + bp1), 8 outputs/thread ----------------
__global__ __launch_bounds__(256) void k_pf1(const float* __restrict__ plk,
                                             const float* __restrict__ W,
                                             const float* __restrict__ bias,
                                             unsigned short* __restrict__ out) {
  int i = blockIdx.x * 256 + threadIdx.x;     // over 16384*80
  int r = i / 80, c8 = (i - r * 80) * 8;
  const float* p = plk + (size_t)r * 6;
  float pv[6];
#pragma unroll
  for (int j = 0; j < 6; j++) pv[j] = p[j];
  u16x8 o;
#pragma unroll
  for (int u = 0; u < 8; u++) {
    int c = c8 + u;
    float a = bias[c];
#pragma unroll
    for (int j = 0; j < 6; j++) a += pv[j] * W[j * HID_ + c];
    o[u] = f2u(a / (1.f + __expf(-a)));
  }
  *(u16x8*)&out[(size_t)r * HID_ + c8] = o;
}

// ---------------- fused pf2-GEMM (z=0) + Q-GEMM (z=1), BK=64, XCD-swizzled --------
// z=0: pf2 = pf1 @ wp2T^T + bp2          (A bf16 via glds)
// z=1: q_lin = rope(hidden @ wqT^T + bq) * 0.125*log2e   (A f32 via VGPR)
__global__ __launch_bounds__(256) void k_gemm_fused(const unsigned short* __restrict__ pf1,
                                                    const float* __restrict__ hidden,
                                                    const unsigned short* __restrict__ wp2T,
                                                    const unsigned short* __restrict__ wqT,
                                                    const float* __restrict__ bp2,
                                                    const float* __restrict__ bq,
                                                    unsigned short* __restrict__ pf2,
                                                    unsigned short* __restrict__ q_lin,
                                                    const float* __restrict__ bev_xy) {
  __shared__ unsigned short As[2][128 * 32];
  __shared__ unsigned short Bs[2][128 * 32];
  const int z = blockIdx.z;
  const int bx = blockIdx.x;
  const int xcd = bx & 7, jj = bx >> 3;
  const int bm = ((jj / 5) * 8 + xcd) * 128;   // same-bm blocks -> same XCD (L2 reuse)
  const int bn = (jj % 5) * 128;
  const int K = 640, N = 640;
  const unsigned short* BT = z ? wqT : wp2T;
  const float* bias = z ? bq : bp2;
  unsigned short* C = z ? q_lin : pf2;

  const int t = threadIdx.x, wv = t >> 6, lane = t & 63;
  const int lc = lane & 15, quad = lane >> 4;
  const int wm = (wv >> 1) * 64, wn = (wv & 1) * 64;
  f32x4 acc[4][4];
  f32x4 zero = {0.f, 0.f, 0.f, 0.f};
#pragma unroll
  for (int i = 0; i < 4; i++)
#pragma unroll
    for (int j = 0; j < 4; j++) acc[i][j] = zero;
  const int srow = wv * 32 + (lane >> 2);
  const int sc8 = (lane & 3) * 8;

  for (int k0 = 0; k0 < K; k0 += 64) {
    __syncthreads();
    if (z == 0) {
#pragma unroll
      for (int h2 = 0; h2 < 2; h2++)
#pragma unroll
        for (int i = 0; i < 2; i++)
          glds16(pf1 + (size_t)(bm + srow + i * 16) * K + k0 + h2 * 32 + sc8,
                 &As[h2][(wv * 32 + i * 16) * 32]);
    } else {
      const int r4 = t >> 2, c4 = (t & 3) * 8;
#pragma unroll
      for (int h2 = 0; h2 < 2; h2++)
#pragma unroll
        for (int i = 0; i < 2; i++) {
          const float* ap = hidden + (size_t)(bm + r4 + i * 64) * K + k0 + h2 * 32 + c4;
          float4 a0 = *(const float4*)ap, a1 = *(const float4*)(ap + 4);
          u16x8 u = { f2u(a0.x), f2u(a0.y), f2u(a0.z), f2u(a0.w),
                      f2u(a1.x), f2u(a1.y), f2u(a1.z), f2u(a1.w) };
          *(u16x8*)&As[h2][(r4 + i * 64) * 32 + c4] = u;
        }
    }
#pragma unroll
    for (int h2 = 0; h2 < 2; h2++)
#pragma unroll
      for (int i = 0; i < 2; i++)
        glds16(BT + (size_t)(bn + srow + i * 16) * K + k0 + h2 * 32 + sc8,
               &Bs[h2][(wv * 32 + i * 16) * 32]);
    __syncthreads();
#pragma unroll
    for (int h2 = 0; h2 < 2; h2++) {
      bf16x8 af[4], bfr[4];
#pragma unroll
      for (int mt = 0; mt < 4; mt++) af[mt]  = *(const bf16x8*)&As[h2][(wm + mt * 16 + lc) * 32 + quad * 8];
#pragma unroll
      for (int nt = 0; nt < 4; nt++) bfr[nt] = *(const bf16x8*)&Bs[h2][(wn + nt * 16 + lc) * 32 + quad * 8];
#pragma unroll
      for (int mt = 0; mt < 4; mt++)
#pragma unroll
        for (int nt = 0; nt < 4; nt++) acc[mt][nt] = mfma16(af[mt], bfr[nt], acc[mt][nt]);
    }
  }

  float bsv[4];
#pragma unroll
  for (int nt = 0; nt < 4; nt++) bsv[nt] = bias[bn + wn + nt * 16 + lc];
  const float inv = __builtin_amdgcn_exp2f(-(float)lc * 0.8304820237218407f);
  const float qscale = 0.18033688011112042f;   // 0.125 * log2(e)

#pragma unroll
  for (int mt = 0; mt < 4; mt++) {
    int row = bm + wm + mt * 16 + quad * 4;
#pragma unroll
    for (int r = 0; r < 4; r++) {
      unsigned short* crow = C + (size_t)(row + r) * N + bn + wn + lc;
      float v0 = acc[mt][0][r] + bsv[0];
      float v1 = acc[mt][1][r] + bsv[1];
      float v2 = acc[mt][2][r] + bsv[2];
      float v3 = acc[mt][3][r] + bsv[3];
      if (z) {
        float2 xy = *(const float2*)&bev_xy[(size_t)(row + r) * 2];
        float s0, c0, s1, c1;
        __sincosf(xy.x * inv, &s0, &c0);
        __sincosf(xy.y * inv, &s1, &c1);
        float n0 = (v0 * c0 - v2 * s0) * qscale;
        float n2 = (v0 * s0 + v2 * c0) * qscale;
        float n1 = (v1 * c1 - v3 * s1) * qscale;
        float n3 = (v1 * s1 + v3 * c1) * qscale;
        v0 = n0; v1 = n1; v2 = n2; v3 = n3;
      }
      crow[0]  = f2u(v0);
      crow[16] = f2u(v1);
      crow[32] = f2u(v2);
      crow[48] = f2u(v3);
    }
  }
}

// ---------------- KV GEMM, BK=64: K->k_lin (rope), V->vT (transposed epilogue) ------
__global__ __launch_bounds__(256) void k_gemm_kv(const unsigned short* __restrict__ sn,
                                                 const unsigned short* __restrict__ kvT,
                                                 const float* __restrict__ bias_kv,
                                                 unsigned short* __restrict__ k_lin,
                                                 unsigned short* __restrict__ vT,
                                                 const float* __restrict__ sat_xy) {
  __shared__ unsigned short As[2][128 * 32];
  __shared__ unsigned short Bs[2][128 * 32];
  const int bx = blockIdx.x;
  const int xcd = bx & 7, jj = bx >> 3;
  const int bm = ((jj / 10) * 8 + xcd) * 128;
  const int bn = (jj % 10) * 128;
  const int K = 768;
  const int t = threadIdx.x, wv = t >> 6, lane = t & 63;
  const int lc = lane & 15, quad = lane >> 4;
  const int wm = (wv >> 1) * 64, wn = (wv & 1) * 64;
  f32x4 acc[4][4];
  f32x4 zero = {0.f, 0.f, 0.f, 0.f};
#pragma unroll
  for (int i = 0; i < 4; i++)
#pragma unroll
    for (int j = 0; j < 4; j++) acc[i][j] = zero;
  const int srow = wv * 32 + (lane >> 2);
  const int sc8 = (lane & 3) * 8;

  for (int k0 = 0; k0 < K; k0 += 64) {
    __syncthreads();
#pragma unroll
    for (int h2 = 0; h2 < 2; h2++)
#pragma unroll
      for (int i = 0; i < 2; i++) {
        glds16(sn  + (size_t)(bm + srow + i * 16) * K + k0 + h2 * 32 + sc8,
               &As[h2][(wv * 32 + i * 16) * 32]);
        glds16(kvT + (size_t)(bn + srow + i * 16) * K + k0 + h2 * 32 + sc8,
               &Bs[h2][(wv * 32 + i * 16) * 32]);
      }
    __syncthreads();
#pragma unroll
    for (int h2 = 0; h2 < 2; h2++) {
      bf16x8 af[4], bfr[4];
#pragma unroll
      for (int mt = 0; mt < 4; mt++) af[mt]  = *(const bf16x8*)&As[h2][(wm + mt * 16 + lc) * 32 + quad * 8];
#pragma unroll
      for (int nt = 0; nt < 4; nt++) bfr[nt] = *(const bf16x8*)&Bs[h2][(wn + nt * 16 + lc) * 32 + quad * 8];
#pragma unroll
      for (int mt = 0; mt < 4; mt++)
#pragma unroll
        for (int nt = 0; nt < 4; nt++) acc[mt][nt] = mfma16(af[mt], bfr[nt], acc[mt][nt]);
    }
  }

  float bsv[4];
#pragma unroll
  for (int nt = 0; nt < 4; nt++) bsv[nt] = bias_kv[bn + wn + nt * 16 + lc];
  const bool isV = (bn >= HID_);   // 128-tiles don't straddle the 640 boundary
  const float inv = __builtin_amdgcn_exp2f(-(float)lc * 0.8304820237218407f);

  if (!isV) {
    // K half: rope, write k_lin[row][col], row = b*1024+key
#pragma unroll
    for (int mt = 0; mt < 4; mt++) {
      int row = bm + wm + mt * 16 + quad * 4;
#pragma unroll
      for (int r = 0; r < 4; r++) {
        unsigned short* crow = k_lin + (size_t)(row + r) * HID_ + bn + wn + lc;
        float v0 = acc[mt][0][r] + bsv[0];
        float v1 = acc[mt][1][r] + bsv[1];
        float v2 = acc[mt][2][r] + bsv[2];
        float v3 = acc[mt][3][r] + bsv[3];
        float2 xy = *(const float2*)&sat_xy[(size_t)(row + r) * 2];
        float s0, c0, s1, c1;
        __sincosf(xy.x * inv, &s0, &c0);
        __sincosf(xy.y * inv, &s1, &c1);
        crow[0]  = f2u(v0 * c0 - v2 * s0);
        crow[32] = f2u(v0 * s0 + v2 * c0);
        crow[16] = f2u(v1 * c1 - v3 * s1);
        crow[48] = f2u(v1 * s1 + v3 * c1);
      }
    }
  } else {
    // V half: write transposed vT[b][d][key], 4 consecutive keys per lane -> 8B store
#pragma unroll
    for (int mt = 0; mt < 4; mt++) {
      int row0 = bm + wm + mt * 16 + quad * 4;
      int bidx = row0 >> 10, key0 = row0 & 1023;
#pragma unroll
      for (int nt = 0; nt < 4; nt++) {
        int d = bn - HID_ + wn + nt * 16 + lc;
        bf16x4 v;
#pragma unroll
        for (int r = 0; r < 4; r++) v[r] = (bf16_t)(acc[mt][nt][r] + bsv[nt]);
        *(bf16x4*)(vT + ((size_t)(bidx * HID_ + d) << 10) + key0) = v;
      }
    }
  }
}

// ---------------- gate = sigmoid(LN(hidden + pf2) @ Wg + bg) ----------------
__global__ __launch_bounds__(256) void k_gate(const float* __restrict__ hid,
                                              const unsigned short* __restrict__ pf2,
                                              const float* __restrict__ g,
                                              const float* __restrict__ be,
                                              const float* __restrict__ Wg,
                                              const float* __restrict__ bg,
                                              const float* __restrict__ vm,
                                              float* __restrict__ gate_buf,
                                              float* __restrict__ lg_buf) {
  int r = blockIdx.x;
  const float* hr = hid + (size_t)r * HID_;
  const unsigned short* pr = pf2 + (size_t)r * HID_;
  int t = threadIdx.x;
  __shared__ float xb[HID_];
  __shared__ float sb[8];
  float s = 0.f, ss = 0.f;
  for (int c = t; c < HID_; c += 256) {
    float x = hr[c] + u2f(pr[c]);
    xb[c] = x; s += x; ss += x * x;
  }
  for (int o = 32; o; o >>= 1) { s += __shfl_xor(s, o); ss += __shfl_xor(ss, o); }
  if ((t & 63) == 0) { sb[t >> 6] = s; sb[4 + (t >> 6)] = ss; }
  __syncthreads();
  s  = sb[0] + sb[1] + sb[2] + sb[3];
  ss = sb[4] + sb[5] + sb[6] + sb[7];
  float m = s * (1.f / HID_);
  float rstd = rsqrtf(ss * (1.f / HID_) - m * m + 1e-5f);
  float dacc = 0.f;
  for (int c = t; c < HID_; c += 256)
    dacc += ((xb[c] - m) * rstd * g[c] + be[c]) * Wg[c];
  for (int o = 32; o; o >>= 1) dacc += __shfl_xor(dacc, o);
  __syncthreads();
  if ((t & 63) == 0) sb[t >> 6] = dacc;
  __syncthreads();
  if (t == 0) {
    float dsum = sb[0] + sb[1] + sb[2] + sb[3] + bg[0];
    float gate = 1.f / (1.f + __expf(-dsum));
    float v = vm[r];
    gate_buf[r] = (v > 0.5f) ? gate : 0.f;
    lg_buf[r]   = (v > 0.5f) ? 0.f : gate;
  }
}

// ---------------- attention: staged-LDS, 128q/block, 32q/wave, no-max exp2 softmax --
__global__ __launch_bounds__(256) void k_attn(const unsigned short* __restrict__ q_lin,
                                              const unsigned short* __restrict__ k_lin,
                                              const unsigned short* __restrict__ vT,
                                              const float* __restrict__ gate_buf,
                                              float* __restrict__ out) {
  __shared__ unsigned short Ks[64 * 72];
  __shared__ unsigned short Vt[64 * 72];
  __shared__ unsigned short Pt[4][32 * 72];
  const int qb = blockIdx.x * 128;
  const int bh = blockIdx.y;
  const int b = bh / NH_, h = bh - b * NH_;
  const int t = threadIdx.x, wv = t >> 6, lane = t & 63;
  const int lc = lane & 15, quad = lane >> 4;
  unsigned short* myPt = &Pt[wv][0];

  const unsigned short* qbase = q_lin + (size_t)(b * SQ_ + qb + wv * 32 + lc) * HID_ + h * HD_;
  bf16x8 qf[2][2];
#pragma unroll
  for (int g = 0; g < 2; g++) {
    qf[g][0] = *(const bf16x8*)(qbase + (size_t)g * 16 * HID_ + quad * 8);
    qf[g][1] = *(const bf16x8*)(qbase + (size_t)g * 16 * HID_ + 32 + quad * 8);
  }
  f32x4 zero = {0.f, 0.f, 0.f, 0.f};
  f32x4 O[2][4];
#pragma unroll
  for (int g = 0; g < 2; g++)
#pragma unroll
    for (int dt = 0; dt < 4; dt++) O[g][dt] = zero;
  float l_run[2] = {0.f, 0.f};

  const unsigned short* Kg = k_lin + (size_t)b * SK_ * HID_ + h * HD_;
  const unsigned short* Vg = vT + ((size_t)b * HID_ + h * HD_) * SK_;
  const int srow = t >> 3, scol = (t & 7) * 8;

  for (int kc = 0; kc < SK_; kc += 64) {
    __syncthreads();
#pragma unroll
    for (int i = 0; i < 2; i++) {
      int row = srow + i * 32;
      *(u16x8*)&Ks[row * 72 + scol] = *(const u16x8*)(Kg + (size_t)(kc + row) * HID_ + scol);
      *(u16x8*)&Vt[row * 72 + scol] = *(const u16x8*)(Vg + (size_t)row * SK_ + kc + scol);
    }
    __syncthreads();

    f32x4 ST[2][4];
#pragma unroll
    for (int kt = 0; kt < 4; kt++) {
      bf16x8 ka0 = *(const bf16x8*)&Ks[(kt * 16 + lc) * 72 + quad * 8];
      bf16x8 ka1 = *(const bf16x8*)&Ks[(kt * 16 + lc) * 72 + 32 + quad * 8];
#pragma unroll
      for (int g = 0; g < 2; g++)
        ST[g][kt] = mfma16(ka1, qf[g][1], mfma16(ka0, qf[g][0], zero));
    }
#pragma unroll
    for (int g = 0; g < 2; g++) {
      float rs = 0.f;
#pragma unroll
      for (int kt = 0; kt < 4; kt++) {
        bf16x4 pk;
#pragma unroll
        for (int r = 0; r < 4; r++) {
          float p = __builtin_amdgcn_exp2f(ST[g][kt][r]);
          rs += p;
          pk[r] = (bf16_t)p;
        }
        *(bf16x4*)&myPt[(g * 16 + lc) * 72 + kt * 16 + quad * 4] = pk;
      }
      rs += __shfl_xor(rs, 16);
      rs += __shfl_xor(rs, 32);
      l_run[g] += rs;
    }
#pragma unroll
    for (int ks = 0; ks < 2; ks++) {
      bf16x8 va[4];
#pragma unroll
      for (int dt = 0; dt < 4; dt++)
        va[dt] = *(const bf16x8*)&Vt[(dt * 16 + lc) * 72 + ks * 32 + quad * 8];
#pragma unroll
      for (int g = 0; g < 2; g++) {
        bf16x8 pb = *(const bf16x8*)&myPt[(g * 16 + lc) * 72 + ks * 32 + quad * 8];
#pragma unroll
        for (int dt = 0; dt < 4; dt++)
          O[g][dt] = mfma16(va[dt], pb, O[g][dt]);
      }
    }
  }

#pragma unroll
  for (int g = 0; g < 2; g++) {
    int rg = b * SQ_ + qb + wv * 32 + g * 16 + lc;
    float gv = gate_buf[rg] / l_run[g];
    float* orow = out + (size_t)rg * HID_ + h * HD_;
#pragma unroll
    for (int dt = 0; dt < 4; dt++) {
      f32x4 o4 = O[g][dt] * gv;
      *(f32x4*)&orow[dt * 16 + quad * 4] = o4;
    }
  }
}

// ---------------- loss reduction ----------------
__global__ __launch_bounds__(256) void k_loss(const float* __restrict__ lg,
                                              const float* __restrict__ vm,
                                              float* __restrict__ out_loss) {
  int t = threadIdx.x;
  float s = 0.f, cnt = 0.f;
  for (int i = t; i < B_ * SQ_; i += 256) {
    s += lg[i];
    cnt += (vm[i] > 0.5f) ? 0.f : 1.f;
  }
  __shared__ float sb[8];
  for (int o = 32; o; o >>= 1) { s += __shfl_xor(s, o); cnt += __shfl_xor(cnt, o); }
  if ((t & 63) == 0) { sb[t >> 6] = s; sb[4 + (t >> 6)] = cnt; }
  __syncthreads();
  if (t == 0) {
    s   = sb[0] + sb[1] + sb[2] + sb[3];
    cnt = sb[4] + sb[5] + sb[6] + sb[7];
    out_loss[0] = s / fmaxf(cnt, 1.f) * 0.05f;
  }
}

extern "C" void kernel_launch(void* const* d_in, const int* in_sizes, int n_in,
                              void* d_out, int out_size, void* d_ws, size_t ws_size,
                              hipStream_t stream) {
  (void)in_sizes; (void)n_in; (void)out_size; (void)ws_size;
  const float* hidden = (const float*)d_in[0];
  const float* sat    = (const float*)d_in[1];
  const float* sat_xy = (const float*)d_in[2];
  const float* bev_xy = (const float*)d_in[3];
  const float* plk    = (const float*)d_in[4];
  const float* vm     = (const float*)d_in[5];
  const float* Wq     = (const float*)d_in[6];
  const float* bq     = (const float*)d_in[7];
  const float* slg    = (const float*)d_in[8];
  const float* slb    = (const float*)d_in[9];
  const float* Wk     = (const float*)d_in[10];
  const float* bk     = (const float*)d_in[11];
  const float* Wv     = (const float*)d_in[12];
  const float* bv     = (const float*)d_in[13];
  const float* Wp1    = (const float*)d_in[14];
  const float* bp1    = (const float*)d_in[15];
  const float* Wp2    = (const float*)d_in[16];
  const float* bp2    = (const float*)d_in[17];
  const float* glg    = (const float*)d_in[18];
  const float* glb    = (const float*)d_in[19];
  const float* Wg     = (const float*)d_in[20];
  const float* bg     = (const float*)d_in[21];
  float* out = (float*)d_out;

  char* ws = (char*)d_ws;
  size_t off = 0;
  auto alloc = [&](size_t bytes) -> char* {
    char* p = ws + off;
    off += (bytes + 255) & ~(size_t)255;
    return p;
  };
  // regP: pf1 (dead after fused GEMM) -> reused for k_lin + vT
  char* regP = alloc((size_t)16384 * 640 * 2);
  unsigned short* pf1   = (unsigned short*)regP;
  unsigned short* k_lin = (unsigned short*)regP;                                    // 4096*640
  unsigned short* vT    = (unsigned short*)(regP + (size_t)4096 * 640 * 2);        // 4*640*1024
  unsigned short* pf2   = (unsigned short*)alloc((size_t)16384 * 640 * 2);
  unsigned short* q_lin = (unsigned short*)alloc((size_t)16384 * 640 * 2);
  unsigned short* sn    = (unsigned short*)alloc((size_t)4096 * 768 * 2);
  unsigned short* wqT   = (unsigned short*)alloc((size_t)640 * 640 * 2);
  unsigned short* kvT   = (unsigned short*)alloc((size_t)1280 * 768 * 2);
  unsigned short* wp2T  = (unsigned short*)alloc((size_t)640 * 640 * 2);
  float* bias_kv  = (float*)alloc(1280 * 4);
  float* gate_buf = (float*)alloc(16384 * 4);
  float* lg_buf   = (float*)alloc(16384 * 4);

  // 1) weight prep
  {
    dim3 g(120, 4);
    k_transpose4<<<g, 256, 0, stream>>>(Wq, Wk, Wv, Wp2, wqT, kvT, wp2T);
  }
  k_concat_bias<<<5, 256, 0, stream>>>(bk, bv, bias_kv);

  // 2) small producers
  k_pf1<<<16384 * 80 / 256, 256, 0, stream>>>(plk, Wp1, bp1, pf1);
  k_satln<<<4096, 256, 0, stream>>>(sat, slg, slb, sn);

  // 3) fused pf2 + Q GEMM (1280 blocks)
  {
    dim3 g(640, 1, 2);
    k_gemm_fused<<<g, 256, 0, stream>>>(pf1, hidden, wp2T, wqT, bp2, bq, pf2, q_lin, bev_xy);
  }
  // 4) KV GEMM -> k_lin (rope) + vT (transposed); overwrites dead pf1 region
  k_gemm_kv<<<320, 256, 0, stream>>>(sn, kvT, bias_kv, k_lin, vT, sat_xy);

  // 5) gate
  k_gate<<<16384, 256, 0, stream>>>(hidden, pf2, glg, glb, Wg, bg, vm, gate_buf, lg_buf);

  // 6) attention + loss
  {
    dim3 g(SQ_ / 128, B_ * NH_);
    k_attn<<<g, 256, 0, stream>>>(q_lin, k_lin, vT, gate_buf, out);
  }
  k_loss<<<1, 256, 0, stream>>>(lg_buf, vm, out + (size_t)B_ * SQ_ * HID_);
}

// Round 6
// 309.077 us; speedup vs baseline: 1.6020x; 1.1464x over previous
//
#include <hip/hip_runtime.h>
#include <cstdint>
#include <cstddef>

#define B_    4
#define SQ_   4096
#define SK_   1024
#define HID_  640
#define SATD_ 768
#define NH_   10
#define HD_   64

typedef __bf16 bf16_t;
typedef __bf16 bf16x4 __attribute__((ext_vector_type(4)));
typedef __bf16 bf16x8 __attribute__((ext_vector_type(8)));
typedef float  f32x4  __attribute__((ext_vector_type(4)));
typedef unsigned short u16x8 __attribute__((ext_vector_type(8)));

static __device__ __forceinline__ unsigned short f2u(float f) {
  bf16_t b = (bf16_t)f;
  return __builtin_bit_cast(unsigned short, b);
}
static __device__ __forceinline__ float u2f(unsigned short u) {
  return (float)__builtin_bit_cast(bf16_t, u);
}
static __device__ __forceinline__ f32x4 mfma16(bf16x8 a, bf16x8 b, f32x4 c) {
  return __builtin_amdgcn_mfma_f32_16x16x32_bf16(a, b, c, 0, 0, 0);
}
static __device__ __forceinline__ void glds16(const unsigned short* g, unsigned short* l) {
  __builtin_amdgcn_global_load_lds((const __attribute__((address_space(1))) void*)g,
                                   (__attribute__((address_space(3))) void*)l, 16, 0, 0);
}

// ================= fused prep: weight transposes + bias concat + satLN + pf1 =======
// grid segments: [0,480) transposes, [480,485) concat, [485,4581) satln, [4581,9701) pf1
__global__ __launch_bounds__(256) void k_prep(const float* __restrict__ Wq,
                                              const float* __restrict__ Wk,
                                              const float* __restrict__ Wv,
                                              const float* __restrict__ Wp2,
                                              unsigned short* __restrict__ wqT,
                                              unsigned short* __restrict__ kvT,
                                              unsigned short* __restrict__ wp2T,
                                              const float* __restrict__ bk,
                                              const float* __restrict__ bv,
                                              float* __restrict__ bias_kv,
                                              const float* __restrict__ sat,
                                              const float* __restrict__ slg,
                                              const float* __restrict__ slb,
                                              unsigned short* __restrict__ sn,
                                              const float* __restrict__ plk,
                                              const float* __restrict__ Wp1,
                                              const float* __restrict__ bp1,
                                              unsigned short* __restrict__ pf1) {
  __shared__ unsigned short tile[64 * 65];
  __shared__ float sb[8];
  const int bx = blockIdx.x, t = threadIdx.x;

  if (bx < 480) {                      // ---- weight transpose, 4 segs x 120 blocks
    int seg = bx / 120, inner = bx % 120;
    const float* W; unsigned short* D; int K;
    if (seg == 0)      { W = Wq;  D = wqT;  K = 640; }
    else if (seg == 1) { W = Wk;  D = kvT;  K = 768; }
    else if (seg == 2) { W = Wv;  D = kvT + (size_t)640 * 768; K = 768; }
    else               { W = Wp2; D = wp2T; K = 640; }
    const int ktiles = K / 64;
    int kt = inner % ktiles, ntile = inner / ktiles;
    if (ntile >= 10) return;
    const int k0 = kt * 64, n0 = ntile * 64;
    const int r = t >> 3, c8 = (t & 7) * 8;
#pragma unroll
    for (int i = 0; i < 2; i++) {
      int row = r + i * 32;
      const float* wp = W + (size_t)(k0 + row) * HID_ + n0 + c8;
      float4 a0 = *(const float4*)wp, a1 = *(const float4*)(wp + 4);
      tile[(c8 + 0) * 65 + row] = f2u(a0.x);
      tile[(c8 + 1) * 65 + row] = f2u(a0.y);
      tile[(c8 + 2) * 65 + row] = f2u(a0.z);
      tile[(c8 + 3) * 65 + row] = f2u(a0.w);
      tile[(c8 + 4) * 65 + row] = f2u(a1.x);
      tile[(c8 + 5) * 65 + row] = f2u(a1.y);
      tile[(c8 + 6) * 65 + row] = f2u(a1.z);
      tile[(c8 + 7) * 65 + row] = f2u(a1.w);
    }
    __syncthreads();
#pragma unroll
    for (int i = 0; i < 2; i++) {
      int nl = r + i * 32;
      u16x8 o;
#pragma unroll
      for (int u = 0; u < 8; u++) o[u] = tile[nl * 65 + c8 + u];
      *(u16x8*)(D + (size_t)(n0 + nl) * K + k0 + c8) = o;
    }
  } else if (bx < 485) {               // ---- bias concat
    int i = (bx - 480) * 256 + t;
    if (i < HID_) bias_kv[i] = bk[i];
    else if (i < 2 * HID_) bias_kv[i] = bv[i - HID_];
  } else if (bx < 4581) {              // ---- sat LayerNorm
    int r = bx - 485;
    const float* xr = sat + (size_t)r * SATD_;
    float v0 = xr[t], v1 = xr[t + 256], v2 = xr[t + 512];
    float s = v0 + v1 + v2;
    float ss = v0 * v0 + v1 * v1 + v2 * v2;
    for (int o = 32; o; o >>= 1) { s += __shfl_xor(s, o); ss += __shfl_xor(ss, o); }
    if ((t & 63) == 0) { sb[t >> 6] = s; sb[4 + (t >> 6)] = ss; }
    __syncthreads();
    s  = sb[0] + sb[1] + sb[2] + sb[3];
    ss = sb[4] + sb[5] + sb[6] + sb[7];
    float m = s * (1.f / SATD_);
    float rstd = rsqrtf(ss * (1.f / SATD_) - m * m + 1e-5f);
    unsigned short* orow = sn + (size_t)r * SATD_;
    orow[t]       = f2u((v0 - m) * rstd * slg[t]       + slb[t]);
    orow[t + 256] = f2u((v1 - m) * rstd * slg[t + 256] + slb[t + 256]);
    orow[t + 512] = f2u((v2 - m) * rstd * slg[t + 512] + slb[t + 512]);
  } else {                             // ---- pf1 = silu(plucker @ Wp1 + bp1)
    int i = (bx - 4581) * 256 + t;     // over 16384*80
    int r = i / 80, c8 = (i - r * 80) * 8;
    const float* p = plk + (size_t)r * 6;
    float pv[6];
#pragma unroll
    for (int j = 0; j < 6; j++) pv[j] = p[j];
    u16x8 o;
#pragma unroll
    for (int u = 0; u < 8; u++) {
      int c = c8 + u;
      float a = bp1[c];
#pragma unroll
      for (int j = 0; j < 6; j++) a += pv[j] * Wp1[j * HID_ + c];
      o[u] = f2u(a / (1.f + __expf(-a)));
    }
    *(u16x8*)&pf1[(size_t)r * HID_ + c8] = o;
  }
}

// ================= mega-GEMM: z=0 pf2, z=1 Q(+rope,f32 A), z=2 KV(+rope,+V^T) ======
__global__ __launch_bounds__(256) void k_gemm3(const unsigned short* __restrict__ pf1,
                                               const float* __restrict__ hidden,
                                               const unsigned short* __restrict__ sn,
                                               const unsigned short* __restrict__ wp2T,
                                               const unsigned short* __restrict__ wqT,
                                               const unsigned short* __restrict__ kvT,
                                               const float* __restrict__ bp2,
                                               const float* __restrict__ bq,
                                               const float* __restrict__ bias_kv,
                                               unsigned short* __restrict__ pf2,
                                               unsigned short* __restrict__ q_lin,
                                               unsigned short* __restrict__ k_lin,
                                               unsigned short* __restrict__ vT,
                                               const float* __restrict__ bev_xy,
                                               const float* __restrict__ sat_xy) {
  __shared__ unsigned short As[2][128 * 32];
  __shared__ unsigned short Bs[2][128 * 32];
  const int z = blockIdx.z;
  const int bx = blockIdx.x;
  int bm, bn, K;
  const unsigned short* BT;
  const float* bias;
  if (z == 2) {
    if (bx >= 320) return;
    const int xcd = bx & 7, jj = bx >> 3;
    bm = ((jj / 10) * 8 + xcd) * 128;
    bn = (jj % 10) * 128;
    K = 768; BT = kvT; bias = bias_kv;
  } else {
    const int xcd = bx & 7, jj = bx >> 3;
    bm = ((jj / 5) * 8 + xcd) * 128;
    bn = (jj % 5) * 128;
    K = 640;
    BT = z ? wqT : wp2T;
    bias = z ? bq : bp2;
  }

  const int t = threadIdx.x, wv = t >> 6, lane = t & 63;
  const int lc = lane & 15, quad = lane >> 4;
  const int wm = (wv >> 1) * 64, wn = (wv & 1) * 64;
  f32x4 acc[4][4];
  f32x4 zero = {0.f, 0.f, 0.f, 0.f};
#pragma unroll
  for (int i = 0; i < 4; i++)
#pragma unroll
    for (int j = 0; j < 4; j++) acc[i][j] = zero;
  const int srow = wv * 32 + (lane >> 2);
  const int sc8 = (lane & 3) * 8;

  for (int k0 = 0; k0 < K; k0 += 64) {
    __syncthreads();
    if (z == 0) {
#pragma unroll
      for (int h2 = 0; h2 < 2; h2++)
#pragma unroll
        for (int i = 0; i < 2; i++)
          glds16(pf1 + (size_t)(bm + srow + i * 16) * K + k0 + h2 * 32 + sc8,
                 &As[h2][(wv * 32 + i * 16) * 32]);
    } else if (z == 2) {
#pragma unroll
      for (int h2 = 0; h2 < 2; h2++)
#pragma unroll
        for (int i = 0; i < 2; i++)
          glds16(sn + (size_t)(bm + srow + i * 16) * K + k0 + h2 * 32 + sc8,
                 &As[h2][(wv * 32 + i * 16) * 32]);
    } else {
      const int r4 = t >> 2, c4 = (t & 3) * 8;
#pragma unroll
      for (int h2 = 0; h2 < 2; h2++)
#pragma unroll
        for (int i = 0; i < 2; i++) {
          const float* ap = hidden + (size_t)(bm + r4 + i * 64) * K + k0 + h2 * 32 + c4;
          float4 a0 = *(const float4*)ap, a1 = *(const float4*)(ap + 4);
          u16x8 u = { f2u(a0.x), f2u(a0.y), f2u(a0.z), f2u(a0.w),
                      f2u(a1.x), f2u(a1.y), f2u(a1.z), f2u(a1.w) };
          *(u16x8*)&As[h2][(r4 + i * 64) * 32 + c4] = u;
        }
    }
#pragma unroll
    for (int h2 = 0; h2 < 2; h2++)
#pragma unroll
      for (int i = 0; i < 2; i++)
        glds16(BT + (size_t)(bn + srow + i * 16) * K + k0 + h2 * 32 + sc8,
               &Bs[h2][(wv * 32 + i * 16) * 32]);
    __syncthreads();
#pragma unroll
    for (int h2 = 0; h2 < 2; h2++) {
      bf16x8 af[4], bfr[4];
#pragma unroll
      for (int mt = 0; mt < 4; mt++) af[mt]  = *(const bf16x8*)&As[h2][(wm + mt * 16 + lc) * 32 + quad * 8];
#pragma unroll
      for (int nt = 0; nt < 4; nt++) bfr[nt] = *(const bf16x8*)&Bs[h2][(wn + nt * 16 + lc) * 32 + quad * 8];
#pragma unroll
      for (int mt = 0; mt < 4; mt++)
#pragma unroll
        for (int nt = 0; nt < 4; nt++) acc[mt][nt] = mfma16(af[mt], bfr[nt], acc[mt][nt]);
    }
  }

  float bsv[4];
#pragma unroll
  for (int nt = 0; nt < 4; nt++) bsv[nt] = bias[bn + wn + nt * 16 + lc];
  const float inv = __builtin_amdgcn_exp2f(-(float)lc * 0.8304820237218407f);

  if (z == 0) {
#pragma unroll
    for (int mt = 0; mt < 4; mt++) {
      int row = bm + wm + mt * 16 + quad * 4;
#pragma unroll
      for (int r = 0; r < 4; r++) {
        unsigned short* crow = pf2 + (size_t)(row + r) * HID_ + bn + wn + lc;
        crow[0]  = f2u(acc[mt][0][r] + bsv[0]);
        crow[16] = f2u(acc[mt][1][r] + bsv[1]);
        crow[32] = f2u(acc[mt][2][r] + bsv[2]);
        crow[48] = f2u(acc[mt][3][r] + bsv[3]);
      }
    }
  } else if (z == 1) {
    const float qscale = 0.18033688011112042f;   // 0.125 * log2(e)
#pragma unroll
    for (int mt = 0; mt < 4; mt++) {
      int row = bm + wm + mt * 16 + quad * 4;
#pragma unroll
      for (int r = 0; r < 4; r++) {
        unsigned short* crow = q_lin + (size_t)(row + r) * HID_ + bn + wn + lc;
        float v0 = acc[mt][0][r] + bsv[0];
        float v1 = acc[mt][1][r] + bsv[1];
        float v2 = acc[mt][2][r] + bsv[2];
        float v3 = acc[mt][3][r] + bsv[3];
        float2 xy = *(const float2*)&bev_xy[(size_t)(row + r) * 2];
        float s0, c0, s1, c1;
        __sincosf(xy.x * inv, &s0, &c0);
        __sincosf(xy.y * inv, &s1, &c1);
        crow[0]  = f2u((v0 * c0 - v2 * s0) * qscale);
        crow[32] = f2u((v0 * s0 + v2 * c0) * qscale);
        crow[16] = f2u((v1 * c1 - v3 * s1) * qscale);
        crow[48] = f2u((v1 * s1 + v3 * c1) * qscale);
      }
    }
  } else if (bn < HID_) {
    // K half: rope -> k_lin
#pragma unroll
    for (int mt = 0; mt < 4; mt++) {
      int row = bm + wm + mt * 16 + quad * 4;
#pragma unroll
      for (int r = 0; r < 4; r++) {
        unsigned short* crow = k_lin + (size_t)(row + r) * HID_ + bn + wn + lc;
        float v0 = acc[mt][0][r] + bsv[0];
        float v1 = acc[mt][1][r] + bsv[1];
        float v2 = acc[mt][2][r] + bsv[2];
        float v3 = acc[mt][3][r] + bsv[3];
        float2 xy = *(const float2*)&sat_xy[(size_t)(row + r) * 2];
        float s0, c0, s1, c1;
        __sincosf(xy.x * inv, &s0, &c0);
        __sincosf(xy.y * inv, &s1, &c1);
        crow[0]  = f2u(v0 * c0 - v2 * s0);
        crow[32] = f2u(v0 * s0 + v2 * c0);
        crow[16] = f2u(v1 * c1 - v3 * s1);
        crow[48] = f2u(v1 * s1 + v3 * c1);
      }
    }
  } else {
    // V half: transposed write vT[b][d][key]
#pragma unroll
    for (int mt = 0; mt < 4; mt++) {
      int row0 = bm + wm + mt * 16 + quad * 4;
      int bidx = row0 >> 10, key0 = row0 & 1023;
#pragma unroll
      for (int nt = 0; nt < 4; nt++) {
        int d = bn - HID_ + wn + nt * 16 + lc;
        bf16x4 v;
#pragma unroll
        for (int r = 0; r < 4; r++) v[r] = (bf16_t)(acc[mt][nt][r] + bsv[nt]);
        *(bf16x4*)(vT + ((size_t)(bidx * HID_ + d) << 10) + key0) = v;
      }
    }
  }
}

// ================= gate: one wave per row, register-resident, no LDS ================
__global__ __launch_bounds__(256) void k_gate(const float* __restrict__ hid,
                                              const unsigned short* __restrict__ pf2,
                                              const float* __restrict__ g,
                                              const float* __restrict__ be,
                                              const float* __restrict__ Wg,
                                              const float* __restrict__ bg,
                                              const float* __restrict__ vm,
                                              float* __restrict__ gate_buf,
                                              float* __restrict__ lg_buf) {
  const int row = blockIdx.x * 4 + (threadIdx.x >> 6);
  const int lane = threadIdx.x & 63;
  const float* hr = hid + (size_t)row * HID_;
  const unsigned short* pr = pf2 + (size_t)row * HID_;
  float x[10];
  float s = 0.f, ss = 0.f;
#pragma unroll
  for (int u = 0; u < 10; u++) {
    int c = u * 64 + lane;
    float v = hr[c] + u2f(pr[c]);
    x[u] = v; s += v; ss += v * v;
  }
#pragma unroll
  for (int o = 32; o; o >>= 1) { s += __shfl_xor(s, o); ss += __shfl_xor(ss, o); }
  float m = s * (1.f / HID_);
  float rstd = rsqrtf(ss * (1.f / HID_) - m * m + 1e-5f);
  float d = 0.f;
#pragma unroll
  for (int u = 0; u < 10; u++) {
    int c = u * 64 + lane;
    d += ((x[u] - m) * rstd * g[c] + be[c]) * Wg[c];
  }
#pragma unroll
  for (int o = 32; o; o >>= 1) d += __shfl_xor(d, o);
  if (lane == 0) {
    float gate = 1.f / (1.f + __expf(-(d + bg[0])));
    float v = vm[row];
    gate_buf[row] = (v > 0.5f) ? gate : 0.f;
    lg_buf[row]   = (v > 0.5f) ? 0.f : gate;
  }
}

// ================= attention: staged LDS + register prefetch double-buffer ==========
__global__ __launch_bounds__(256) void k_attn(const unsigned short* __restrict__ q_lin,
                                              const unsigned short* __restrict__ k_lin,
                                              const unsigned short* __restrict__ vT,
                                              const float* __restrict__ gate_buf,
                                              float* __restrict__ out) {
  __shared__ unsigned short Ks[64 * 72];
  __shared__ unsigned short Vt[64 * 72];
  __shared__ unsigned short Pt[4][32 * 72];
  const int qb = blockIdx.x * 128;
  const int bh = blockIdx.y;
  const int b = bh / NH_, h = bh - b * NH_;
  const int t = threadIdx.x, wv = t >> 6, lane = t & 63;
  const int lc = lane & 15, quad = lane >> 4;
  unsigned short* myPt = &Pt[wv][0];

  const unsigned short* qbase = q_lin + (size_t)(b * SQ_ + qb + wv * 32 + lc) * HID_ + h * HD_;
  bf16x8 qf[2][2];
#pragma unroll
  for (int g = 0; g < 2; g++) {
    qf[g][0] = *(const bf16x8*)(qbase + (size_t)g * 16 * HID_ + quad * 8);
    qf[g][1] = *(const bf16x8*)(qbase + (size_t)g * 16 * HID_ + 32 + quad * 8);
  }
  f32x4 zero = {0.f, 0.f, 0.f, 0.f};
  f32x4 O[2][4];
#pragma unroll
  for (int g = 0; g < 2; g++)
#pragma unroll
    for (int dt = 0; dt < 4; dt++) O[g][dt] = zero;
  float l_run[2] = {0.f, 0.f};

  const unsigned short* Kg = k_lin + (size_t)b * SK_ * HID_ + h * HD_;
  const unsigned short* Vg = vT + ((size_t)b * HID_ + h * HD_) * SK_;
  const int srow = t >> 3, scol = (t & 7) * 8;

  // prologue prefetch of chunk 0
  u16x8 kpre[2], vpre[2];
#pragma unroll
  for (int i = 0; i < 2; i++) {
    kpre[i] = *(const u16x8*)(Kg + (size_t)(srow + i * 32) * HID_ + scol);
    vpre[i] = *(const u16x8*)(Vg + (size_t)(srow + i * 32) * SK_ + scol);
  }

  for (int kc = 0; kc < SK_; kc += 64) {
    __syncthreads();
#pragma unroll
    for (int i = 0; i < 2; i++) {
      int row = srow + i * 32;
      *(u16x8*)&Ks[row * 72 + scol] = kpre[i];
      *(u16x8*)&Vt[row * 72 + scol] = vpre[i];
    }
    __syncthreads();
    if (kc + 64 < SK_) {
#pragma unroll
      for (int i = 0; i < 2; i++) {
        kpre[i] = *(const u16x8*)(Kg + (size_t)(kc + 64 + srow + i * 32) * HID_ + scol);
        vpre[i] = *(const u16x8*)(Vg + (size_t)(srow + i * 32) * SK_ + kc + 64 + scol);
      }
    }

    f32x4 ST[2][4];
#pragma unroll
    for (int kt = 0; kt < 4; kt++) {
      bf16x8 ka0 = *(const bf16x8*)&Ks[(kt * 16 + lc) * 72 + quad * 8];
      bf16x8 ka1 = *(const bf16x8*)&Ks[(kt * 16 + lc) * 72 + 32 + quad * 8];
#pragma unroll
      for (int g = 0; g < 2; g++)
        ST[g][kt] = mfma16(ka1, qf[g][1], mfma16(ka0, qf[g][0], zero));
    }
#pragma unroll
    for (int g = 0; g < 2; g++) {
      float rs = 0.f;
#pragma unroll
      for (int kt = 0; kt < 4; kt++) {
        bf16x4 pk;
#pragma unroll
        for (int r = 0; r < 4; r++) {
          float p = __builtin_amdgcn_exp2f(ST[g][kt][r]);
          rs += p;
          pk[r] = (bf16_t)p;
        }
        *(bf16x4*)&myPt[(g * 16 + lc) * 72 + kt * 16 + quad * 4] = pk;
      }
      rs += __shfl_xor(rs, 16);
      rs += __shfl_xor(rs, 32);
      l_run[g] += rs;
    }
#pragma unroll
    for (int ks = 0; ks < 2; ks++) {
      bf16x8 va[4];
#pragma unroll
      for (int dt = 0; dt < 4; dt++)
        va[dt] = *(const bf16x8*)&Vt[(dt * 16 + lc) * 72 + ks * 32 + quad * 8];
#pragma unroll
      for (int g = 0; g < 2; g++) {
        bf16x8 pb = *(const bf16x8*)&myPt[(g * 16 + lc) * 72 + ks * 32 + quad * 8];
#pragma unroll
        for (int dt = 0; dt < 4; dt++)
          O[g][dt] = mfma16(va[dt], pb, O[g][dt]);
      }
    }
  }

#pragma unroll
  for (int g = 0; g < 2; g++) {
    int rg = b * SQ_ + qb + wv * 32 + g * 16 + lc;
    float gv = gate_buf[rg] / l_run[g];
    float* orow = out + (size_t)rg * HID_ + h * HD_;
#pragma unroll
    for (int dt = 0; dt < 4; dt++) {
      f32x4 o4 = O[g][dt] * gv;
      *(f32x4*)&orow[dt * 16 + quad * 4] = o4;
    }
  }
}

// ================= loss reduction =================
__global__ __launch_bounds__(256) void k_loss(const float* __restrict__ lg,
                                              const float* __restrict__ vm,
                                              float* __restrict__ out_loss) {
  int t = threadIdx.x;
  float s = 0.f, cnt = 0.f;
  for (int i = t; i < B_ * SQ_; i += 256) {
    s += lg[i];
    cnt += (vm[i] > 0.5f) ? 0.f : 1.f;
  }
  __shared__ float sb[8];
  for (int o = 32; o; o >>= 1) { s += __shfl_xor(s, o); cnt += __shfl_xor(cnt, o); }
  if ((t & 63) == 0) { sb[t >> 6] = s; sb[4 + (t >> 6)] = cnt; }
  __syncthreads();
  if (t == 0) {
    s   = sb[0] + sb[1] + sb[2] + sb[3];
    cnt = sb[4] + sb[5] + sb[6] + sb[7];
    out_loss[0] = s / fmaxf(cnt, 1.f) * 0.05f;
  }
}

extern "C" void kernel_launch(void* const* d_in, const int* in_sizes, int n_in,
                              void* d_out, int out_size, void* d_ws, size_t ws_size,
                              hipStream_t stream) {
  (void)in_sizes; (void)n_in; (void)out_size; (void)ws_size;
  const float* hidden = (const float*)d_in[0];
  const float* sat    = (const float*)d_in[1];
  const float* sat_xy = (const float*)d_in[2];
  const float* bev_xy = (const float*)d_in[3];
  const float* plk    = (const float*)d_in[4];
  const float* vm     = (const float*)d_in[5];
  const float* Wq     = (const float*)d_in[6];
  const float* bq     = (const float*)d_in[7];
  const float* slg    = (const float*)d_in[8];
  const float* slb    = (const float*)d_in[9];
  const float* Wk     = (const float*)d_in[10];
  const float* bk     = (const float*)d_in[11];
  const float* Wv     = (const float*)d_in[12];
  const float* bv     = (const float*)d_in[13];
  const float* Wp1    = (const float*)d_in[14];
  const float* bp1    = (const float*)d_in[15];
  const float* Wp2    = (const float*)d_in[16];
  const float* bp2    = (const float*)d_in[17];
  const float* glg    = (const float*)d_in[18];
  const float* glb    = (const float*)d_in[19];
  const float* Wg     = (const float*)d_in[20];
  const float* bg     = (const float*)d_in[21];
  float* out = (float*)d_out;

  char* ws = (char*)d_ws;
  size_t off = 0;
  auto alloc = [&](size_t bytes) -> char* {
    char* p = ws + off;
    off += (bytes + 255) & ~(size_t)255;
    return p;
  };
  // pf2 lives in d_out (41.9 MB): written by gemm3, read by k_gate, then d_out is
  // fully overwritten by k_attn + k_loss (stream-ordered). Keeps ws ~62 MB.
  unsigned short* pf2   = (unsigned short*)d_out;
  unsigned short* pf1   = (unsigned short*)alloc((size_t)16384 * 640 * 2);
  unsigned short* q_lin = (unsigned short*)alloc((size_t)16384 * 640 * 2);
  unsigned short* k_lin = (unsigned short*)alloc((size_t)4096 * 640 * 2);
  unsigned short* vT    = (unsigned short*)alloc((size_t)B_ * HID_ * SK_ * 2);
  unsigned short* sn    = (unsigned short*)alloc((size_t)4096 * 768 * 2);
  unsigned short* wqT   = (unsigned short*)alloc((size_t)640 * 640 * 2);
  unsigned short* kvT   = (unsigned short*)alloc((size_t)1280 * 768 * 2);
  unsigned short* wp2T  = (unsigned short*)alloc((size_t)640 * 640 * 2);
  float* bias_kv  = (float*)alloc(1280 * 4);
  float* gate_buf = (float*)alloc(16384 * 4);
  float* lg_buf   = (float*)alloc(16384 * 4);

  // 1) fused prep (transposes + concat + satLN + pf1)
  k_prep<<<9701, 256, 0, stream>>>(Wq, Wk, Wv, Wp2, wqT, kvT, wp2T,
                                   bk, bv, bias_kv,
                                   sat, slg, slb, sn,
                                   plk, Wp1, bp1, pf1);

  // 2) mega-GEMM: pf2 + Q(+rope) + KV(+rope, V transposed)
  {
    dim3 g(640, 1, 3);
    k_gemm3<<<g, 256, 0, stream>>>(pf1, hidden, sn, wp2T, wqT, kvT,
                                   bp2, bq, bias_kv,
                                   pf2, q_lin, k_lin, vT, bev_xy, sat_xy);
  }

  // 3) gate (wave per row)
  k_gate<<<4096, 256, 0, stream>>>(hidden, pf2, glg, glb, Wg, bg, vm, gate_buf, lg_buf);

  // 4) attention (overwrites d_out, incl. the pf2 staging area)
  {
    dim3 g(SQ_ / 128, B_ * NH_);
    k_attn<<<g, 256, 0, stream>>>(q_lin, k_lin, vT, gate_buf, out);
  }
  // 5) loss
  k_loss<<<1, 256, 0, stream>>>(lg_buf, vm, out + (size_t)B_ * SQ_ * HID_);
}